// Round 6
// baseline (382.434 us; speedup 1.0000x reference)
//
#include <hip/hip_runtime.h>
#include <math.h>

#define BN_EPS 1e-3f

typedef __attribute__((ext_vector_type(8))) unsigned short ushort8v;
typedef __attribute__((ext_vector_type(8))) short short8v;
typedef __attribute__((ext_vector_type(4))) float f32x4;

__device__ __forceinline__ float4 f4load(const float* p) {
    return *reinterpret_cast<const float4*>(p);
}
__device__ __forceinline__ float bf2f(unsigned short u) {
    union { unsigned int i; float f; } w; w.i = ((unsigned int)u) << 16; return w.f;
}
__device__ __forceinline__ unsigned short f2bf(float f) {
    union { float fv; unsigned int i; } w; w.fv = f;
    unsigned int lsb = (w.i >> 16) & 1u;
    w.i += 0x7fffu + lsb;             // round-to-nearest-even
    return (unsigned short)(w.i >> 16);
}

// ---------------- Weight prep: k[tap][cin][cout] f32 -> Wt[tap][cout][cin] bf16
template<int CIN, int COUT>
__device__ __forceinline__ void wprep_body(
    const float* __restrict__ k, unsigned short* __restrict__ wt, int blk)
{
    int idx = blk * 256 + (int)threadIdx.x;
    constexpr int CI8 = CIN / 8;
    if (idx >= 27 * COUT * CI8) return;
    int ci0 = (idx % CI8) * 8;
    int c   = (idx / CI8) % COUT;
    int t   = idx / (CI8 * COUT);
    ushort8v o;
    #pragma unroll
    for (int j = 0; j < 8; ++j)
        o[j] = f2bf(k[(size_t)(t * CIN + ci0 + j) * COUT + c]);
    *reinterpret_cast<ushort8v*>(wt + ((size_t)t * COUT + c) * CIN + ci0) = o;
}

__global__ __launch_bounds__(256) void wprep_all(
    const float* __restrict__ k1, const float* __restrict__ k2, const float* __restrict__ k3,
    unsigned short* __restrict__ w1, unsigned short* __restrict__ w2, unsigned short* __restrict__ w3)
{
    int b = blockIdx.x;
    if (b < 27)       wprep_body<32, 64>(k1, w1, b);
    else if (b < 135) wprep_body<64, 128>(k2, w2, b - 27);
    else              wprep_body<128, 256>(k3, w3, b - 135);
}

// ---------------- Block 0: cin=1, cout=32, 96^3 -> 48^3 (fp32 in, bf16 out)
__global__ __launch_bounds__(256) void conv0_v3(
    const float* __restrict__ x, const float* __restrict__ k,
    const float* __restrict__ b, const float* __restrict__ g,
    const float* __restrict__ be, const float* __restrict__ m,
    const float* __restrict__ v, unsigned short* __restrict__ y)
{
    int t = blockIdx.x * 256 + threadIdx.x;
    int co8 = t & 3;  t >>= 2;
    int owq = t % 6;  t /= 6;
    int oh  = t % 48; t /= 48;
    int od  = t % 48; int n = t / 48;    // grid exact
    const int c0 = co8 * 8;

    float acc[8][8];
    #pragma unroll
    for (int q = 0; q < 8; ++q)
        #pragma unroll
        for (int j = 0; j < 8; ++j) acc[q][j] = 0.f;

    const int id0 = od * 2, ih0 = oh * 2, iwb = owq * 16;
    const bool wEdge = (owq == 5);

    #pragma unroll 1
    for (int kd = 0; kd < 3; ++kd) {
        int id = id0 + kd; bool dok = id < 96;
        #pragma unroll
        for (int kh = 0; kh < 3; ++kh) {
            int ih = ih0 + kh; bool rok = dok && (ih < 96);
            const float* xr = x + ((size_t)(n * 96 + (rok ? id : 0)) * 96 + (rok ? ih : 0)) * 96 + iwb;
            float4 rA = f4load(xr);
            float4 rB = f4load(xr + 4);
            float4 rC = f4load(xr + 8);
            float4 rD = f4load(xr + 12);
            float r16 = xr[wEdge ? 15 : 16];
            float r[17] = {rA.x, rA.y, rA.z, rA.w, rB.x, rB.y, rB.z, rB.w,
                           rC.x, rC.y, rC.z, rC.w, rD.x, rD.y, rD.z, rD.w, r16};
            if (wEdge) r[16] = 0.f;
            if (!rok) {
                #pragma unroll
                for (int j = 0; j < 17; ++j) r[j] = 0.f;
            }
            #pragma unroll
            for (int kw = 0; kw < 3; ++kw) {
                const float* wp = k + ((kd * 3 + kh) * 3 + kw) * 32 + c0;
                float4 wA = f4load(wp), wB = f4load(wp + 4);
                float w8[8] = {wA.x, wA.y, wA.z, wA.w, wB.x, wB.y, wB.z, wB.w};
                #pragma unroll
                for (int q = 0; q < 8; ++q) {
                    float xv = r[2 * q + kw];
                    #pragma unroll
                    for (int j = 0; j < 8; ++j) acc[q][j] += xv * w8[j];
                }
            }
        }
    }

    float S[8], T[8];
    #pragma unroll
    for (int j = 0; j < 8; ++j) {
        int c = c0 + j;
        float sc = g[c] * rsqrtf(v[c] + BN_EPS);
        S[j] = sc;
        T[j] = (b[c] - m[c]) * sc + be[c];
    }
    #pragma unroll
    for (int q = 0; q < 8; ++q) {
        int ow = owq * 8 + q;
        unsigned short* yp = y + (((size_t)(n * 48 + od) * 48 + oh) * 48 + ow) * 32 + c0;
        ushort8v o;
        #pragma unroll
        for (int j = 0; j < 8; ++j)
            o[j] = f2bf(fmaxf(acc[q][j] * S[j] + T[j], 0.f));
        *reinterpret_cast<ushort8v*>(yp) = o;
    }
}

// ---------------- MFMA implicit-GEMM conv, register-blocked.
// Wave: MW M-subtiles (16 voxels each) x NSW N-subtiles (16 couts each).
// Block: 4 waves = (4/NH) M-groups x NH cout-groups.
// Tiling chosen occupancy-first: latency-bound regime (R5 post-mortem),
// so grid >= ~2 blocks/CU matters more than per-wave load amortization.
template<int CIN, int COUT, int INS, int OUTS, int MW, int NSW, int NH>
__global__ __launch_bounds__(256) void conv_mfma(
    const unsigned short* __restrict__ x, const unsigned short* __restrict__ wt,
    const float* __restrict__ b, const float* __restrict__ g,
    const float* __restrict__ be, const float* __restrict__ m,
    const float* __restrict__ v, unsigned short* __restrict__ y)
{
    constexpr int NS = COUT / 16;
    constexpr int KS = CIN / 32;
    constexpr int MGROUPS = 4 / NH;
    constexpr int MTILE = MGROUPS * MW * 16;
    static_assert(NS == NSW * NH && 4 % NH == 0, "tiling");

    const int l   = threadIdx.x & 63;
    const int wid = threadIdx.x >> 6;
    const int sg  = l >> 4;
    const int lr  = l & 15;

    const int mgroup = wid / NH;
    const int ngroup = wid % NH;
    const int coutBase = ngroup * NSW * 16;
    const int vwave = blockIdx.x * MTILE + mgroup * MW * 16;

    const unsigned short* ap0[MW];
    bool dE[MW], hE[MW], wE[MW];
    #pragma unroll
    for (int mi = 0; mi < MW; ++mi) {
        int vA = vwave + mi * 16 + lr;
        int owA = vA % OUTS; int t1 = vA / OUTS;
        int ohA = t1 % OUTS; int t2 = t1 / OUTS;
        int odA = t2 % OUTS; int nA = t2 / OUTS;
        ap0[mi] = x + ((((size_t)nA * INS + 2 * odA) * INS + 2 * ohA) * INS + 2 * owA) * CIN + sg * 8;
        dE[mi] = (odA == OUTS - 1); hE[mi] = (ohA == OUTS - 1); wE[mi] = (owA == OUTS - 1);
    }

    const unsigned short* bp0 = wt + ((size_t)coutBase + lr) * CIN + sg * 8;

    f32x4 acc[MW][NSW];
    #pragma unroll
    for (int mi = 0; mi < MW; ++mi)
        #pragma unroll
        for (int ns = 0; ns < NSW; ++ns) acc[mi][ns] = (f32x4){0.f, 0.f, 0.f, 0.f};

    #pragma unroll 1
    for (int kd = 0; kd < 3; ++kd) {
        #pragma unroll
        for (int kh = 0; kh < 3; ++kh) {
            #pragma unroll
            for (int kw = 0; kw < 3; ++kw) {
                const int tap = (kd * 3 + kh) * 3 + kw;
                const size_t aoff = (size_t)((kd * INS + kh) * INS + kw) * CIN;
                const unsigned short* bp = bp0 + (size_t)tap * COUT * CIN;
                #pragma unroll
                for (int ks = 0; ks < KS; ++ks) {
                    short8v a[MW], bf[NSW];
                    #pragma unroll
                    for (int mi = 0; mi < MW; ++mi) {
                        bool skip = ((kd == 2) && dE[mi]) || ((kh == 2) && hE[mi]) || ((kw == 2) && wE[mi]);
                        short8v tv = {0, 0, 0, 0, 0, 0, 0, 0};
                        if (!skip) tv = *reinterpret_cast<const short8v*>(ap0[mi] + aoff + ks * 32);
                        a[mi] = tv;
                    }
                    #pragma unroll
                    for (int ns = 0; ns < NSW; ++ns)
                        bf[ns] = *reinterpret_cast<const short8v*>(bp + (size_t)ns * 16 * CIN + ks * 32);
                    #pragma unroll
                    for (int mi = 0; mi < MW; ++mi)
                        #pragma unroll
                        for (int ns = 0; ns < NSW; ++ns)
                            acc[mi][ns] = __builtin_amdgcn_mfma_f32_16x16x32_bf16(a[mi], bf[ns], acc[mi][ns], 0, 0, 0);
                }
            }
        }
    }

    float S[NSW], T[NSW];
    #pragma unroll
    for (int ns = 0; ns < NSW; ++ns) {
        int c = coutBase + ns * 16 + lr;
        float sc = g[c] * rsqrtf(v[c] + BN_EPS);
        S[ns] = sc;
        T[ns] = (b[c] - m[c]) * sc + be[c];
    }
    #pragma unroll
    for (int mi = 0; mi < MW; ++mi) {
        #pragma unroll
        for (int i = 0; i < 4; ++i) {
            int vD = vwave + mi * 16 + sg * 4 + i;
            int ow = vD % OUTS; int u1 = vD / OUTS;
            int oh = u1 % OUTS; int u2 = u1 / OUTS;
            int od = u2 % OUTS; int n = u2 / OUTS;
            unsigned short* yp =
                y + ((((size_t)n * OUTS + od) * OUTS + oh) * OUTS + ow) * COUT + coutBase + lr;
            #pragma unroll
            for (int ns = 0; ns < NSW; ++ns)
                yp[ns * 16] = f2bf(fmaxf(acc[mi][ns][i] * S[ns] + T[ns], 0.f));
        }
    }
}

// ---------------- Head: mean pool + 1x1 conv + BN/ReLU + 1x1 conv + top2 softmax
__global__ __launch_bounds__(256) void head_kernel(
    const unsigned short* __restrict__ x4,   // (16, 6,6,6, 256) bf16
    const float* __restrict__ w1k, const float* __restrict__ w1b,
    const float* __restrict__ wg,  const float* __restrict__ wbe,
    const float* __restrict__ wm,  const float* __restrict__ wv,
    const float* __restrict__ w2k, const float* __restrict__ w2b,
    float* __restrict__ out)
{
    __shared__ float part[8][256];
    __shared__ float h[256];
    __shared__ float r[256];
    __shared__ float logits[8];

    const int n = blockIdx.x;
    const int t = threadIdx.x;
    const int c8 = t & 31;
    const int pg = t >> 5;

    const unsigned short* xb = x4 + (size_t)n * 216 * 256 + c8 * 8;
    float s[8] = {0.f, 0.f, 0.f, 0.f, 0.f, 0.f, 0.f, 0.f};
    for (int i = pg; i < 216; i += 8) {
        ushort8v v8 = *reinterpret_cast<const ushort8v*>(xb + (size_t)i * 256);
        #pragma unroll
        for (int j = 0; j < 8; ++j) s[j] += bf2f(v8[j]);
    }
    #pragma unroll
    for (int j = 0; j < 8; ++j) part[pg][c8 * 8 + j] = s[j];
    __syncthreads();

    float a = 0.f;
    #pragma unroll
    for (int gi = 0; gi < 8; ++gi) a += part[gi][t];
    h[t] = a * (1.0f / 216.0f);
    __syncthreads();

    float acc = w1b[t];
    #pragma unroll 4
    for (int ci = 0; ci < 256; ++ci) acc += h[ci] * w1k[ci * 256 + t];
    float sc = wg[t] * rsqrtf(wv[t] + BN_EPS);
    acc = (acc - wm[t]) * sc + wbe[t];
    r[t] = fmaxf(acc, 0.f);
    __syncthreads();

    if (t < 8) {
        float a2 = w2b[t];
        for (int ci = 0; ci < 256; ++ci) a2 += r[ci] * w2k[ci * 8 + t];
        logits[t] = a2;
    }
    __syncthreads();

    if (t == 0) {
        float m1 = -INFINITY, m2 = -INFINITY;
        for (int e = 0; e < 8; ++e) {
            float val = logits[e];
            if (val > m1) { m2 = m1; m1 = val; }
            else if (val > m2) { m2 = val; }
        }
        float thr = m2;
        float ex[8]; float sum = 0.f;
        for (int e = 0; e < 8; ++e) {
            float val = (logits[e] >= thr) ? logits[e] : -INFINITY;
            ex[e] = expf(val - m1);
            sum += ex[e];
        }
        float inv = 1.0f / sum;
        for (int e = 0; e < 8; ++e) out[n * 8 + e] = ex[e] * inv;
    }
}

extern "C" void kernel_launch(void* const* d_in, const int* in_sizes, int n_in,
                              void* d_out, int out_size, void* d_ws, size_t ws_size,
                              hipStream_t stream) {
    const float* x   = (const float*)d_in[0];
    const float* k0  = (const float*)d_in[1];
    const float* b0  = (const float*)d_in[2];
    const float* g0  = (const float*)d_in[3];
    const float* be0 = (const float*)d_in[4];
    const float* m0  = (const float*)d_in[5];
    const float* v0  = (const float*)d_in[6];
    const float* k1  = (const float*)d_in[7];
    const float* b1  = (const float*)d_in[8];
    const float* g1  = (const float*)d_in[9];
    const float* be1 = (const float*)d_in[10];
    const float* m1  = (const float*)d_in[11];
    const float* v1  = (const float*)d_in[12];
    const float* k2  = (const float*)d_in[13];
    const float* b2  = (const float*)d_in[14];
    const float* g2  = (const float*)d_in[15];
    const float* be2 = (const float*)d_in[16];
    const float* m2  = (const float*)d_in[17];
    const float* v2  = (const float*)d_in[18];
    const float* k3  = (const float*)d_in[19];
    const float* b3  = (const float*)d_in[20];
    const float* g3  = (const float*)d_in[21];
    const float* be3 = (const float*)d_in[22];
    const float* m3  = (const float*)d_in[23];
    const float* v3  = (const float*)d_in[24];
    const float* w1k = (const float*)d_in[25];
    const float* w1b = (const float*)d_in[26];
    const float* wg  = (const float*)d_in[27];
    const float* wbe = (const float*)d_in[28];
    const float* wm  = (const float*)d_in[29];
    const float* wv  = (const float*)d_in[30];
    const float* w2k = (const float*)d_in[31];
    const float* w2b = (const float*)d_in[32];

    unsigned short* x1  = (unsigned short*)d_ws;
    unsigned short* x2  = x1 + 56623104;
    unsigned short* x3  = x2 + 14155776;
    unsigned short* x4  = x3 + 3538944;
    unsigned short* Wt1 = x4 + 884736;
    unsigned short* Wt2 = Wt1 + 55296;
    unsigned short* Wt3 = Wt2 + 221184;

    wprep_all<<<567, 256, 0, stream>>>(k1, k2, k3, Wt1, Wt2, Wt3);
    conv0_v3<<<3456, 256, 0, stream>>>(x, k0, b0, g0, be0, m0, v0, x1);
    // occupancy-first tilings (R5 lesson):
    conv_mfma<32, 64, 48, 24, 2, 4, 1><<<1728, 256, 0, stream>>>(x1, Wt1, b1, g1, be1, m1, v1, x2);
    conv_mfma<64, 128, 24, 12, 1, 4, 2><<<864, 256, 0, stream>>>(x2, Wt2, b2, g2, be2, m2, v2, x3);
    conv_mfma<128, 256, 12, 6, 1, 4, 4><<<216, 256, 0, stream>>>(x3, Wt3, b3, g3, be3, m3, v3, x4);
    head_kernel<<<16, 256, 0, stream>>>(x4, w1k, w1b, wg, wbe, wm, wv, w2k, w2b, (float*)d_out);
}

// Round 7
// 338.737 us; speedup vs baseline: 1.1290x; 1.1290x over previous
//
#include <hip/hip_runtime.h>
#include <math.h>

#define BN_EPS 1e-3f

typedef __attribute__((ext_vector_type(8))) unsigned short ushort8v;
typedef __attribute__((ext_vector_type(8))) short short8v;
typedef __attribute__((ext_vector_type(4))) float f32x4;

__device__ __forceinline__ float4 f4load(const float* p) {
    return *reinterpret_cast<const float4*>(p);
}
__device__ __forceinline__ float bf2f(unsigned short u) {
    union { unsigned int i; float f; } w; w.i = ((unsigned int)u) << 16; return w.f;
}
__device__ __forceinline__ unsigned short f2bf(float f) {
    union { float fv; unsigned int i; } w; w.fv = f;
    unsigned int lsb = (w.i >> 16) & 1u;
    w.i += 0x7fffu + lsb;             // round-to-nearest-even
    return (unsigned short)(w.i >> 16);
}

// ---------------- Weight prep: k[tap][cin][cout] f32 -> Wt[tap][cout][cin] bf16
template<int CIN, int COUT>
__device__ __forceinline__ void wprep_body(
    const float* __restrict__ k, unsigned short* __restrict__ wt, int blk)
{
    int idx = blk * 256 + (int)threadIdx.x;
    constexpr int CI8 = CIN / 8;
    if (idx >= 27 * COUT * CI8) return;
    int ci0 = (idx % CI8) * 8;
    int c   = (idx / CI8) % COUT;
    int t   = idx / (CI8 * COUT);
    ushort8v o;
    #pragma unroll
    for (int j = 0; j < 8; ++j)
        o[j] = f2bf(k[(size_t)(t * CIN + ci0 + j) * COUT + c]);
    *reinterpret_cast<ushort8v*>(wt + ((size_t)t * COUT + c) * CIN + ci0) = o;
}

__global__ __launch_bounds__(256) void wprep_all(
    const float* __restrict__ k1, const float* __restrict__ k2, const float* __restrict__ k3,
    unsigned short* __restrict__ w1, unsigned short* __restrict__ w2, unsigned short* __restrict__ w3)
{
    int b = blockIdx.x;
    if (b < 27)       wprep_body<32, 64>(k1, w1, b);
    else if (b < 135) wprep_body<64, 128>(k2, w2, b - 27);
    else              wprep_body<128, 256>(k3, w3, b - 135);
}

// ---------------- Block 0: cin=1, cout=32, 96^3 -> 48^3 (fp32 in, bf16 out)
__global__ __launch_bounds__(256) void conv0_v3(
    const float* __restrict__ x, const float* __restrict__ k,
    const float* __restrict__ b, const float* __restrict__ g,
    const float* __restrict__ be, const float* __restrict__ m,
    const float* __restrict__ v, unsigned short* __restrict__ y)
{
    int t = blockIdx.x * 256 + threadIdx.x;
    int co8 = t & 3;  t >>= 2;
    int owq = t % 6;  t /= 6;
    int oh  = t % 48; t /= 48;
    int od  = t % 48; int n = t / 48;    // grid exact
    const int c0 = co8 * 8;

    float acc[8][8];
    #pragma unroll
    for (int q = 0; q < 8; ++q)
        #pragma unroll
        for (int j = 0; j < 8; ++j) acc[q][j] = 0.f;

    const int id0 = od * 2, ih0 = oh * 2, iwb = owq * 16;
    const bool wEdge = (owq == 5);

    #pragma unroll 1
    for (int kd = 0; kd < 3; ++kd) {
        int id = id0 + kd; bool dok = id < 96;
        #pragma unroll
        for (int kh = 0; kh < 3; ++kh) {
            int ih = ih0 + kh; bool rok = dok && (ih < 96);
            const float* xr = x + ((size_t)(n * 96 + (rok ? id : 0)) * 96 + (rok ? ih : 0)) * 96 + iwb;
            float4 rA = f4load(xr);
            float4 rB = f4load(xr + 4);
            float4 rC = f4load(xr + 8);
            float4 rD = f4load(xr + 12);
            float r16 = xr[wEdge ? 15 : 16];
            float r[17] = {rA.x, rA.y, rA.z, rA.w, rB.x, rB.y, rB.z, rB.w,
                           rC.x, rC.y, rC.z, rC.w, rD.x, rD.y, rD.z, rD.w, r16};
            if (wEdge) r[16] = 0.f;
            if (!rok) {
                #pragma unroll
                for (int j = 0; j < 17; ++j) r[j] = 0.f;
            }
            #pragma unroll
            for (int kw = 0; kw < 3; ++kw) {
                const float* wp = k + ((kd * 3 + kh) * 3 + kw) * 32 + c0;
                float4 wA = f4load(wp), wB = f4load(wp + 4);
                float w8[8] = {wA.x, wA.y, wA.z, wA.w, wB.x, wB.y, wB.z, wB.w};
                #pragma unroll
                for (int q = 0; q < 8; ++q) {
                    float xv = r[2 * q + kw];
                    #pragma unroll
                    for (int j = 0; j < 8; ++j) acc[q][j] += xv * w8[j];
                }
            }
        }
    }

    float S[8], T[8];
    #pragma unroll
    for (int j = 0; j < 8; ++j) {
        int c = c0 + j;
        float sc = g[c] * rsqrtf(v[c] + BN_EPS);
        S[j] = sc;
        T[j] = (b[c] - m[c]) * sc + be[c];
    }
    #pragma unroll
    for (int q = 0; q < 8; ++q) {
        int ow = owq * 8 + q;
        unsigned short* yp = y + (((size_t)(n * 48 + od) * 48 + oh) * 48 + ow) * 32 + c0;
        ushort8v o;
        #pragma unroll
        for (int j = 0; j < 8; ++j)
            o[j] = f2bf(fmaxf(acc[q][j] * S[j] + T[j], 0.f));
        *reinterpret_cast<ushort8v*>(yp) = o;
    }
}

// ---------------- MFMA implicit-GEMM conv, 2-stage register-pipelined.
// Flattened (tap,ks) loop; fragments for iter i+1 load while iter i MFMAs.
// Ping-pong buffers with static indices only (runtime-indexed arrays spill).
template<int CIN, int COUT, int INS, int OUTS, int MW, int NSW, int NH>
__global__ __launch_bounds__(256) void conv_mfma_p(
    const unsigned short* __restrict__ x, const unsigned short* __restrict__ wt,
    const float* __restrict__ b, const float* __restrict__ g,
    const float* __restrict__ be, const float* __restrict__ m,
    const float* __restrict__ v, unsigned short* __restrict__ y)
{
    constexpr int NS = COUT / 16;
    constexpr int KS = CIN / 32;
    constexpr int NIT = 27 * KS;
    constexpr int MGROUPS = 4 / NH;
    constexpr int MTILE = MGROUPS * MW * 16;
    static_assert(NS == NSW * NH && 4 % NH == 0, "tiling");

    const int l   = threadIdx.x & 63;
    const int wid = threadIdx.x >> 6;
    const int sg  = l >> 4;
    const int lr  = l & 15;

    const int mgroup = wid / NH;
    const int ngroup = wid % NH;
    const int coutBase = ngroup * NSW * 16;
    const int vwave = blockIdx.x * MTILE + mgroup * MW * 16;

    const unsigned short* ap0[MW];
    unsigned smask[MW];   // bit t = 1 -> tap t out of bounds for this lane's voxel
    #pragma unroll
    for (int mi = 0; mi < MW; ++mi) {
        int vA = vwave + mi * 16 + lr;
        int owA = vA % OUTS; int t1 = vA / OUTS;
        int ohA = t1 % OUTS; int t2 = t1 / OUTS;
        int odA = t2 % OUTS; int nA = t2 / OUTS;
        ap0[mi] = x + ((((size_t)nA * INS + 2 * odA) * INS + 2 * ohA) * INS + 2 * owA) * CIN + sg * 8;
        smask[mi] = ((odA == OUTS - 1) ? 0x07FC0000u : 0u)    // kd==2: taps 18..26
                  | ((ohA == OUTS - 1) ? 0x070381C0u : 0u)    // kh==2: taps 6-8,15-17,24-26
                  | ((owA == OUTS - 1) ? 0x04924924u : 0u);   // kw==2: taps 2,5,...,26
    }

    const unsigned short* bp0 = wt + ((size_t)coutBase + lr) * CIN + sg * 8;

    f32x4 acc[MW][NSW];
    #pragma unroll
    for (int mi = 0; mi < MW; ++mi)
        #pragma unroll
        for (int ns = 0; ns < NSW; ++ns) acc[mi][ns] = (f32x4){0.f, 0.f, 0.f, 0.f};

    auto loadf = [&](int it, short8v (&A)[MW], short8v (&B)[NSW]) {
        int tap = (KS == 1) ? it : (it / KS);
        int ks  = (KS == 1) ? 0  : (it - tap * KS);
        int kd = tap / 9;
        int r9 = tap - kd * 9;
        int kh = r9 / 3;
        int kw = r9 - kh * 3;
        const size_t aoff = (size_t)((kd * INS + kh) * INS + kw) * CIN + ks * 32;
        #pragma unroll
        for (int mi = 0; mi < MW; ++mi) {
            short8v tv = {0, 0, 0, 0, 0, 0, 0, 0};
            if (!((smask[mi] >> tap) & 1u))
                tv = *reinterpret_cast<const short8v*>(ap0[mi] + aoff);
            A[mi] = tv;
        }
        const unsigned short* bp = bp0 + (size_t)tap * (COUT * CIN) + ks * 32;
        #pragma unroll
        for (int ns = 0; ns < NSW; ++ns)
            B[ns] = *reinterpret_cast<const short8v*>(bp + (size_t)ns * 16 * CIN);
    };
    auto domfma = [&](short8v (&A)[MW], short8v (&B)[NSW]) {
        #pragma unroll
        for (int mi = 0; mi < MW; ++mi)
            #pragma unroll
            for (int ns = 0; ns < NSW; ++ns)
                acc[mi][ns] = __builtin_amdgcn_mfma_f32_16x16x32_bf16(A[mi], B[ns], acc[mi][ns], 0, 0, 0);
    };

    short8v A0[MW], B0[NSW], A1[MW], B1[NSW];
    loadf(0, A0, B0);
    int it = 0;
    #pragma unroll 1
    for (; it + 1 < NIT; it += 2) {
        loadf(it + 1, A1, B1);
        domfma(A0, B0);
        if (it + 2 < NIT) loadf(it + 2, A0, B0);
        domfma(A1, B1);
    }
    if (it < NIT) domfma(A0, B0);   // odd NIT tail (already loaded)

    float S[NSW], T[NSW];
    #pragma unroll
    for (int ns = 0; ns < NSW; ++ns) {
        int c = coutBase + ns * 16 + lr;
        float sc = g[c] * rsqrtf(v[c] + BN_EPS);
        S[ns] = sc;
        T[ns] = (b[c] - m[c]) * sc + be[c];
    }
    #pragma unroll
    for (int mi = 0; mi < MW; ++mi) {
        #pragma unroll
        for (int i = 0; i < 4; ++i) {
            int vD = vwave + mi * 16 + sg * 4 + i;
            int ow = vD % OUTS; int u1 = vD / OUTS;
            int oh = u1 % OUTS; int u2 = u1 / OUTS;
            int od = u2 % OUTS; int n = u2 / OUTS;
            unsigned short* yp =
                y + ((((size_t)n * OUTS + od) * OUTS + oh) * OUTS + ow) * COUT + coutBase + lr;
            #pragma unroll
            for (int ns = 0; ns < NSW; ++ns)
                yp[ns * 16] = f2bf(fmaxf(acc[mi][ns][i] * S[ns] + T[ns], 0.f));
        }
    }
}

// ---------------- Head: mean pool + 1x1 conv + BN/ReLU + 1x1 conv + top2 softmax
__global__ __launch_bounds__(256) void head_kernel(
    const unsigned short* __restrict__ x4,   // (16, 6,6,6, 256) bf16
    const float* __restrict__ w1k, const float* __restrict__ w1b,
    const float* __restrict__ wg,  const float* __restrict__ wbe,
    const float* __restrict__ wm,  const float* __restrict__ wv,
    const float* __restrict__ w2k, const float* __restrict__ w2b,
    float* __restrict__ out)
{
    __shared__ float part[8][256];
    __shared__ float h[256];
    __shared__ float r[256];
    __shared__ float logits[8];

    const int n = blockIdx.x;
    const int t = threadIdx.x;
    const int c8 = t & 31;
    const int pg = t >> 5;

    const unsigned short* xb = x4 + (size_t)n * 216 * 256 + c8 * 8;
    float s[8] = {0.f, 0.f, 0.f, 0.f, 0.f, 0.f, 0.f, 0.f};
    for (int i = pg; i < 216; i += 8) {
        ushort8v v8 = *reinterpret_cast<const ushort8v*>(xb + (size_t)i * 256);
        #pragma unroll
        for (int j = 0; j < 8; ++j) s[j] += bf2f(v8[j]);
    }
    #pragma unroll
    for (int j = 0; j < 8; ++j) part[pg][c8 * 8 + j] = s[j];
    __syncthreads();

    float a = 0.f;
    #pragma unroll
    for (int gi = 0; gi < 8; ++gi) a += part[gi][t];
    h[t] = a * (1.0f / 216.0f);
    __syncthreads();

    float acc = w1b[t];
    #pragma unroll 4
    for (int ci = 0; ci < 256; ++ci) acc += h[ci] * w1k[ci * 256 + t];
    float sc = wg[t] * rsqrtf(wv[t] + BN_EPS);
    acc = (acc - wm[t]) * sc + wbe[t];
    r[t] = fmaxf(acc, 0.f);
    __syncthreads();

    if (t < 8) {
        float a2 = w2b[t];
        for (int ci = 0; ci < 256; ++ci) a2 += r[ci] * w2k[ci * 8 + t];
        logits[t] = a2;
    }
    __syncthreads();

    if (t == 0) {
        float m1 = -INFINITY, m2 = -INFINITY;
        for (int e = 0; e < 8; ++e) {
            float val = logits[e];
            if (val > m1) { m2 = m1; m1 = val; }
            else if (val > m2) { m2 = val; }
        }
        float thr = m2;
        float ex[8]; float sum = 0.f;
        for (int e = 0; e < 8; ++e) {
            float val = (logits[e] >= thr) ? logits[e] : -INFINITY;
            ex[e] = expf(val - m1);
            sum += ex[e];
        }
        float inv = 1.0f / sum;
        for (int e = 0; e < 8; ++e) out[n * 8 + e] = ex[e] * inv;
    }
}

extern "C" void kernel_launch(void* const* d_in, const int* in_sizes, int n_in,
                              void* d_out, int out_size, void* d_ws, size_t ws_size,
                              hipStream_t stream) {
    const float* x   = (const float*)d_in[0];
    const float* k0  = (const float*)d_in[1];
    const float* b0  = (const float*)d_in[2];
    const float* g0  = (const float*)d_in[3];
    const float* be0 = (const float*)d_in[4];
    const float* m0  = (const float*)d_in[5];
    const float* v0  = (const float*)d_in[6];
    const float* k1  = (const float*)d_in[7];
    const float* b1  = (const float*)d_in[8];
    const float* g1  = (const float*)d_in[9];
    const float* be1 = (const float*)d_in[10];
    const float* m1  = (const float*)d_in[11];
    const float* v1  = (const float*)d_in[12];
    const float* k2  = (const float*)d_in[13];
    const float* b2  = (const float*)d_in[14];
    const float* g2  = (const float*)d_in[15];
    const float* be2 = (const float*)d_in[16];
    const float* m2  = (const float*)d_in[17];
    const float* v2  = (const float*)d_in[18];
    const float* k3  = (const float*)d_in[19];
    const float* b3  = (const float*)d_in[20];
    const float* g3  = (const float*)d_in[21];
    const float* be3 = (const float*)d_in[22];
    const float* m3  = (const float*)d_in[23];
    const float* v3  = (const float*)d_in[24];
    const float* w1k = (const float*)d_in[25];
    const float* w1b = (const float*)d_in[26];
    const float* wg  = (const float*)d_in[27];
    const float* wbe = (const float*)d_in[28];
    const float* wm  = (const float*)d_in[29];
    const float* wv  = (const float*)d_in[30];
    const float* w2k = (const float*)d_in[31];
    const float* w2b = (const float*)d_in[32];

    unsigned short* x1  = (unsigned short*)d_ws;
    unsigned short* x2  = x1 + 56623104;
    unsigned short* x3  = x2 + 14155776;
    unsigned short* x4  = x3 + 3538944;
    unsigned short* Wt1 = x4 + 884736;
    unsigned short* Wt2 = Wt1 + 55296;
    unsigned short* Wt3 = Wt2 + 221184;

    wprep_all<<<567, 256, 0, stream>>>(k1, k2, k3, Wt1, Wt2, Wt3);
    conv0_v3<<<3456, 256, 0, stream>>>(x, k0, b0, g0, be0, m0, v0, x1);
    // pipelined implicit-GEMM convs (R6 lesson: ILP via reg double-buffer,
    // grid >= ~3 blocks/CU where possible):
    conv_mfma_p<32, 64, 48, 24, 4, 4, 1><<<864, 256, 0, stream>>>(x1, Wt1, b1, g1, be1, m1, v1, x2);
    conv_mfma_p<64, 128, 24, 12, 2, 2, 4><<<864, 256, 0, stream>>>(x2, Wt2, b2, g2, be2, m2, v2, x3);
    conv_mfma_p<128, 256, 12, 6, 1, 4, 4><<<216, 256, 0, stream>>>(x3, Wt3, b3, g3, be3, m3, v3, x4);
    head_kernel<<<16, 256, 0, stream>>>(x4, w1k, w1b, wg, wbe, wm, wv, w2k, w2b, (float*)d_out);
}

// Round 8
// 265.093 us; speedup vs baseline: 1.4426x; 1.2778x over previous
//
#include <hip/hip_runtime.h>
#include <math.h>

#define BN_EPS 1e-3f

typedef __attribute__((ext_vector_type(8))) unsigned short ushort8v;
typedef __attribute__((ext_vector_type(8))) short short8v;
typedef __attribute__((ext_vector_type(4))) float f32x4;

__device__ __forceinline__ float4 f4load(const float* p) {
    return *reinterpret_cast<const float4*>(p);
}
__device__ __forceinline__ float bf2f(unsigned short u) {
    union { unsigned int i; float f; } w; w.i = ((unsigned int)u) << 16; return w.f;
}
__device__ __forceinline__ unsigned short f2bf(float f) {
    union { float fv; unsigned int i; } w; w.fv = f;
    unsigned int lsb = (w.i >> 16) & 1u;
    w.i += 0x7fffu + lsb;             // round-to-nearest-even
    return (unsigned short)(w.i >> 16);
}

#define GLOAD_LDS16(g, l)                                                     \
    __builtin_amdgcn_global_load_lds(                                         \
        (const __attribute__((address_space(1))) void*)(const void*)(g),      \
        (__attribute__((address_space(3))) void*)(void*)(l), 16, 0, 0)

// ---------------- Weight prep: k[tap][cin][cout] f32 ->
// frag-order Wt[it][nsg][lane][8] bf16, it = tap*KS+ks, lane = sg*16+lr,
// cout = nsg*16+lr, cin = ks*32+sg*8+j.  16B per (it,nsg,lane) chunk.
template<int CIN, int COUT>
__device__ __forceinline__ void wprep_body(
    const float* __restrict__ k, unsigned short* __restrict__ wt, int blk)
{
    constexpr int NS = COUT / 16;
    constexpr int KS = CIN / 32;
    int idx = blk * 256 + (int)threadIdx.x;
    if (idx >= 27 * KS * NS * 64) return;
    int lane = idx & 63;
    int nsg  = (idx >> 6) % NS;
    int it   = idx / (64 * NS);
    int tap  = it / KS;
    int ks   = it - tap * KS;
    int sg = lane >> 4, lr = lane & 15;
    int cout = nsg * 16 + lr;
    ushort8v o;
    #pragma unroll
    for (int j = 0; j < 8; ++j) {
        int ci = ks * 32 + sg * 8 + j;
        o[j] = f2bf(k[(size_t)(tap * CIN + ci) * COUT + cout]);
    }
    *reinterpret_cast<ushort8v*>(wt + (size_t)idx * 8) = o;
}

__global__ __launch_bounds__(256) void wprep_all(
    const float* __restrict__ k1, const float* __restrict__ k2, const float* __restrict__ k3,
    unsigned short* __restrict__ w1, unsigned short* __restrict__ w2, unsigned short* __restrict__ w3,
    unsigned short* __restrict__ zp)
{
    int b = blockIdx.x;
    if (b < 27)       wprep_body<32, 64>(k1, w1, b);
    else if (b < 135) wprep_body<64, 128>(k2, w2, b - 27);
    else if (b < 567) wprep_body<128, 256>(k3, w3, b - 135);
    else {
        // 1KB zero page for edge-tap A gathers
        reinterpret_cast<unsigned int*>(zp)[threadIdx.x] = 0u;
    }
}

// ---------------- Block 0: cin=1, cout=32, 96^3 -> 48^3 (fp32 in, bf16 out)
__global__ __launch_bounds__(256) void conv0_v3(
    const float* __restrict__ x, const float* __restrict__ k,
    const float* __restrict__ b, const float* __restrict__ g,
    const float* __restrict__ be, const float* __restrict__ m,
    const float* __restrict__ v, unsigned short* __restrict__ y)
{
    int t = blockIdx.x * 256 + threadIdx.x;
    int co8 = t & 3;  t >>= 2;
    int owq = t % 6;  t /= 6;
    int oh  = t % 48; t /= 48;
    int od  = t % 48; int n = t / 48;    // grid exact
    const int c0 = co8 * 8;

    float acc[8][8];
    #pragma unroll
    for (int q = 0; q < 8; ++q)
        #pragma unroll
        for (int j = 0; j < 8; ++j) acc[q][j] = 0.f;

    const int id0 = od * 2, ih0 = oh * 2, iwb = owq * 16;
    const bool wEdge = (owq == 5);

    #pragma unroll 1
    for (int kd = 0; kd < 3; ++kd) {
        int id = id0 + kd; bool dok = id < 96;
        #pragma unroll
        for (int kh = 0; kh < 3; ++kh) {
            int ih = ih0 + kh; bool rok = dok && (ih < 96);
            const float* xr = x + ((size_t)(n * 96 + (rok ? id : 0)) * 96 + (rok ? ih : 0)) * 96 + iwb;
            float4 rA = f4load(xr);
            float4 rB = f4load(xr + 4);
            float4 rC = f4load(xr + 8);
            float4 rD = f4load(xr + 12);
            float r16 = xr[wEdge ? 15 : 16];
            float r[17] = {rA.x, rA.y, rA.z, rA.w, rB.x, rB.y, rB.z, rB.w,
                           rC.x, rC.y, rC.z, rC.w, rD.x, rD.y, rD.z, rD.w, r16};
            if (wEdge) r[16] = 0.f;
            if (!rok) {
                #pragma unroll
                for (int j = 0; j < 17; ++j) r[j] = 0.f;
            }
            #pragma unroll
            for (int kw = 0; kw < 3; ++kw) {
                const float* wp = k + ((kd * 3 + kh) * 3 + kw) * 32 + c0;
                float4 wA = f4load(wp), wB = f4load(wp + 4);
                float w8[8] = {wA.x, wA.y, wA.z, wA.w, wB.x, wB.y, wB.z, wB.w};
                #pragma unroll
                for (int q = 0; q < 8; ++q) {
                    float xv = r[2 * q + kw];
                    #pragma unroll
                    for (int j = 0; j < 8; ++j) acc[q][j] += xv * w8[j];
                }
            }
        }
    }

    float S[8], T[8];
    #pragma unroll
    for (int j = 0; j < 8; ++j) {
        int c = c0 + j;
        float sc = g[c] * rsqrtf(v[c] + BN_EPS);
        S[j] = sc;
        T[j] = (b[c] - m[c]) * sc + be[c];
    }
    #pragma unroll
    for (int q = 0; q < 8; ++q) {
        int ow = owq * 8 + q;
        unsigned short* yp = y + (((size_t)(n * 48 + od) * 48 + oh) * 48 + ow) * 32 + c0;
        ushort8v o;
        #pragma unroll
        for (int j = 0; j < 8; ++j)
            o[j] = f2bf(fmaxf(acc[q][j] * S[j] + T[j], 0.f));
        *reinterpret_cast<ushort8v*>(yp) = o;
    }
}

// ---------------- MFMA implicit-GEMM conv, LDS double-buffered (m97 pattern).
// Per K-step: stage(next tile via global_load_lds) -> ds_read(cur) -> MFMA ->
// __syncthreads (drains vmcnt+lgkm). Weights pre-permuted to fragment order;
// A gathered per-lane straight into frag-order LDS (edge taps -> zero page).
template<int CIN, int COUT, int INS, int OUTS, int MW, int NSW, int NH>
__global__ __launch_bounds__(256, 2) void conv_mfma_lds(
    const unsigned short* __restrict__ x, const unsigned short* __restrict__ wt,
    const unsigned short* __restrict__ zp,
    const float* __restrict__ b, const float* __restrict__ g,
    const float* __restrict__ be, const float* __restrict__ m,
    const float* __restrict__ v, unsigned short* __restrict__ y)
{
    constexpr int NS = COUT / 16;
    constexpr int KS = CIN / 32;
    constexpr int NIT = 27 * KS;
    constexpr int MGROUPS = 4 / NH;
    constexpr int MTILE = MGROUPS * MW * 16;
    constexpr int BSTEP = NS * 1024;            // bytes per B K-step
    constexpr int ASTEP = 4 * MW * 1024;        // bytes per A K-step (4 waves)
    constexpr int STRIDE = BSTEP + ASTEP;
    static_assert(NS == NSW * NH && 4 % NH == 0, "tiling");

    __shared__ __attribute__((aligned(16))) char lds[2 * STRIDE];

    const int l   = threadIdx.x & 63;
    const int wid = threadIdx.x >> 6;
    const int sg  = l >> 4;
    const int lr  = l & 15;

    const int mgroup = wid / NH;
    const int ngroup = wid % NH;
    const int coutBase = ngroup * NSW * 16;
    const int vwave = blockIdx.x * MTILE + mgroup * MW * 16;

    const unsigned short* ap0[MW];
    unsigned smask[MW];   // bit t -> tap t out of bounds for this lane's voxel
    #pragma unroll
    for (int mi = 0; mi < MW; ++mi) {
        int vA = vwave + mi * 16 + lr;
        int owA = vA % OUTS; int t1 = vA / OUTS;
        int ohA = t1 % OUTS; int t2 = t1 / OUTS;
        int odA = t2 % OUTS; int nA = t2 / OUTS;
        ap0[mi] = x + ((((size_t)nA * INS + 2 * odA) * INS + 2 * ohA) * INS + 2 * owA) * CIN + sg * 8;
        smask[mi] = ((odA == OUTS - 1) ? 0x07FC0000u : 0u)
                  | ((ohA == OUTS - 1) ? 0x070381C0u : 0u)
                  | ((owA == OUTS - 1) ? 0x04924924u : 0u);
    }

    const char* wtB = (const char*)wt;
    const unsigned short* zpl = (const unsigned short*)((const char*)zp + l * 16);

    f32x4 acc[MW][NSW];
    #pragma unroll
    for (int mi = 0; mi < MW; ++mi)
        #pragma unroll
        for (int ns = 0; ns < NSW; ++ns) acc[mi][ns] = (f32x4){0.f, 0.f, 0.f, 0.f};

    auto stage = [&](int it, int p) {
        char* dst = &lds[p * STRIDE];
        // B: contiguous frag-order chunk, linear per-lane
        const char* bg = wtB + (size_t)it * BSTEP;
        #pragma unroll
        for (int c = 0; c < BSTEP / 4096; ++c)
            GLOAD_LDS16(bg + c * 4096 + wid * 1024 + l * 16,
                        dst + c * 4096 + wid * 1024);
        // A: per-lane gather into this wave's frag slots
        int tap = (KS == 1) ? it : it / KS;
        int ks  = (KS == 1) ? 0  : it - tap * KS;
        int kd = tap / 9, r9 = tap - kd * 9, kh = r9 / 3, kw = r9 - kh * 3;
        size_t aoff = (size_t)((kd * INS + kh) * INS + kw) * CIN + ks * 32;
        char* adst = dst + BSTEP + wid * (MW * 1024);
        #pragma unroll
        for (int mi = 0; mi < MW; ++mi) {
            const unsigned short* ga =
                ((smask[mi] >> tap) & 1u) ? zpl : (ap0[mi] + aoff);
            GLOAD_LDS16(ga, adst + mi * 1024);
        }
    };

    stage(0, 0);
    __syncthreads();
    int cur = 0;
    #pragma unroll 1
    for (int it = 0; it < NIT; ++it) {
        if (it + 1 < NIT) stage(it + 1, cur ^ 1);
        const char* buf = &lds[cur * STRIDE];
        short8v Bf[NSW], Af[MW];
        #pragma unroll
        for (int ns = 0; ns < NSW; ++ns)
            Bf[ns] = *(const short8v*)(buf + ((ngroup * NSW + ns) * 64 + l) * 16);
        #pragma unroll
        for (int mi = 0; mi < MW; ++mi)
            Af[mi] = *(const short8v*)(buf + BSTEP + (wid * MW + mi) * 1024 + l * 16);
        #pragma unroll
        for (int mi = 0; mi < MW; ++mi)
            #pragma unroll
            for (int ns = 0; ns < NSW; ++ns)
                acc[mi][ns] = __builtin_amdgcn_mfma_f32_16x16x32_bf16(Af[mi], Bf[ns], acc[mi][ns], 0, 0, 0);
        __syncthreads();
        cur ^= 1;
    }

    float S[NSW], T[NSW];
    #pragma unroll
    for (int ns = 0; ns < NSW; ++ns) {
        int c = coutBase + ns * 16 + lr;
        float sc = g[c] * rsqrtf(v[c] + BN_EPS);
        S[ns] = sc;
        T[ns] = (b[c] - m[c]) * sc + be[c];
    }
    #pragma unroll
    for (int mi = 0; mi < MW; ++mi) {
        #pragma unroll
        for (int i = 0; i < 4; ++i) {
            int vD = vwave + mi * 16 + sg * 4 + i;
            int ow = vD % OUTS; int u1 = vD / OUTS;
            int oh = u1 % OUTS; int u2 = u1 / OUTS;
            int od = u2 % OUTS; int n = u2 / OUTS;
            unsigned short* yp =
                y + ((((size_t)n * OUTS + od) * OUTS + oh) * OUTS + ow) * COUT + coutBase + lr;
            #pragma unroll
            for (int ns = 0; ns < NSW; ++ns)
                yp[ns * 16] = f2bf(fmaxf(acc[mi][ns][i] * S[ns] + T[ns], 0.f));
        }
    }
}

// ---------------- Head: mean pool + 1x1 conv + BN/ReLU + 1x1 conv + top2 softmax
__global__ __launch_bounds__(256) void head_kernel(
    const unsigned short* __restrict__ x4,   // (16, 6,6,6, 256) bf16
    const float* __restrict__ w1k, const float* __restrict__ w1b,
    const float* __restrict__ wg,  const float* __restrict__ wbe,
    const float* __restrict__ wm,  const float* __restrict__ wv,
    const float* __restrict__ w2k, const float* __restrict__ w2b,
    float* __restrict__ out)
{
    __shared__ float part[8][256];
    __shared__ float h[256];
    __shared__ float r[256];
    __shared__ float logits[8];

    const int n = blockIdx.x;
    const int t = threadIdx.x;
    const int c8 = t & 31;
    const int pg = t >> 5;

    const unsigned short* xb = x4 + (size_t)n * 216 * 256 + c8 * 8;
    float s[8] = {0.f, 0.f, 0.f, 0.f, 0.f, 0.f, 0.f, 0.f};
    for (int i = pg; i < 216; i += 8) {
        ushort8v v8 = *reinterpret_cast<const ushort8v*>(xb + (size_t)i * 256);
        #pragma unroll
        for (int j = 0; j < 8; ++j) s[j] += bf2f(v8[j]);
    }
    #pragma unroll
    for (int j = 0; j < 8; ++j) part[pg][c8 * 8 + j] = s[j];
    __syncthreads();

    float a = 0.f;
    #pragma unroll
    for (int gi = 0; gi < 8; ++gi) a += part[gi][t];
    h[t] = a * (1.0f / 216.0f);
    __syncthreads();

    float acc = w1b[t];
    #pragma unroll 4
    for (int ci = 0; ci < 256; ++ci) acc += h[ci] * w1k[ci * 256 + t];
    float sc = wg[t] * rsqrtf(wv[t] + BN_EPS);
    acc = (acc - wm[t]) * sc + wbe[t];
    r[t] = fmaxf(acc, 0.f);
    __syncthreads();

    if (t < 8) {
        float a2 = w2b[t];
        for (int ci = 0; ci < 256; ++ci) a2 += r[ci] * w2k[ci * 8 + t];
        logits[t] = a2;
    }
    __syncthreads();

    if (t == 0) {
        float m1 = -INFINITY, m2 = -INFINITY;
        for (int e = 0; e < 8; ++e) {
            float val = logits[e];
            if (val > m1) { m2 = m1; m1 = val; }
            else if (val > m2) { m2 = val; }
        }
        float thr = m2;
        float ex[8]; float sum = 0.f;
        for (int e = 0; e < 8; ++e) {
            float val = (logits[e] >= thr) ? logits[e] : -INFINITY;
            ex[e] = expf(val - m1);
            sum += ex[e];
        }
        float inv = 1.0f / sum;
        for (int e = 0; e < 8; ++e) out[n * 8 + e] = ex[e] * inv;
    }
}

extern "C" void kernel_launch(void* const* d_in, const int* in_sizes, int n_in,
                              void* d_out, int out_size, void* d_ws, size_t ws_size,
                              hipStream_t stream) {
    const float* x   = (const float*)d_in[0];
    const float* k0  = (const float*)d_in[1];
    const float* b0  = (const float*)d_in[2];
    const float* g0  = (const float*)d_in[3];
    const float* be0 = (const float*)d_in[4];
    const float* m0  = (const float*)d_in[5];
    const float* v0  = (const float*)d_in[6];
    const float* k1  = (const float*)d_in[7];
    const float* b1  = (const float*)d_in[8];
    const float* g1  = (const float*)d_in[9];
    const float* be1 = (const float*)d_in[10];
    const float* m1  = (const float*)d_in[11];
    const float* v1  = (const float*)d_in[12];
    const float* k2  = (const float*)d_in[13];
    const float* b2  = (const float*)d_in[14];
    const float* g2  = (const float*)d_in[15];
    const float* be2 = (const float*)d_in[16];
    const float* m2  = (const float*)d_in[17];
    const float* v2  = (const float*)d_in[18];
    const float* k3  = (const float*)d_in[19];
    const float* b3  = (const float*)d_in[20];
    const float* g3  = (const float*)d_in[21];
    const float* be3 = (const float*)d_in[22];
    const float* m3  = (const float*)d_in[23];
    const float* v3  = (const float*)d_in[24];
    const float* w1k = (const float*)d_in[25];
    const float* w1b = (const float*)d_in[26];
    const float* wg  = (const float*)d_in[27];
    const float* wbe = (const float*)d_in[28];
    const float* wm  = (const float*)d_in[29];
    const float* wv  = (const float*)d_in[30];
    const float* w2k = (const float*)d_in[31];
    const float* w2b = (const float*)d_in[32];

    unsigned short* x1  = (unsigned short*)d_ws;
    unsigned short* x2  = x1 + 56623104;
    unsigned short* x3  = x2 + 14155776;
    unsigned short* x4  = x3 + 3538944;
    unsigned short* Wt1 = x4 + 884736;
    unsigned short* Wt2 = Wt1 + 55296;
    unsigned short* Wt3 = Wt2 + 221184;
    unsigned short* zp  = Wt3 + 884736;    // 1KB zero page (512 ushorts)

    wprep_all<<<568, 256, 0, stream>>>(k1, k2, k3, Wt1, Wt2, Wt3, zp);
    conv0_v3<<<3456, 256, 0, stream>>>(x, k0, b0, g0, be0, m0, v0, x1);
    conv_mfma_lds<32, 64, 48, 24, 4, 4, 1><<<864, 256, 0, stream>>>(x1, Wt1, zp, b1, g1, be1, m1, v1, x2);
    conv_mfma_lds<64, 128, 24, 12, 2, 4, 2><<<432, 256, 0, stream>>>(x2, Wt2, zp, b2, g2, be2, m2, v2, x3);
    conv_mfma_lds<128, 256, 12, 6, 1, 4, 4><<<216, 256, 0, stream>>>(x3, Wt3, zp, b3, g3, be3, m3, v3, x4);
    head_kernel<<<16, 256, 0, stream>>>(x4, w1k, w1b, wg, wbe, wm, wv, w2k, w2b, (float*)d_out);
}

// Round 9
// 248.361 us; speedup vs baseline: 1.5398x; 1.0674x over previous
//
#include <hip/hip_runtime.h>
#include <math.h>

#define BN_EPS 1e-3f

typedef __attribute__((ext_vector_type(8))) unsigned short ushort8v;
typedef __attribute__((ext_vector_type(8))) short short8v;
typedef __attribute__((ext_vector_type(4))) float f32x4;

__device__ __forceinline__ float4 f4load(const float* p) {
    return *reinterpret_cast<const float4*>(p);
}
__device__ __forceinline__ float bf2f(unsigned short u) {
    union { unsigned int i; float f; } w; w.i = ((unsigned int)u) << 16; return w.f;
}
__device__ __forceinline__ unsigned short f2bf(float f) {
    union { float fv; unsigned int i; } w; w.fv = f;
    unsigned int lsb = (w.i >> 16) & 1u;
    w.i += 0x7fffu + lsb;             // round-to-nearest-even
    return (unsigned short)(w.i >> 16);
}

#define GLOAD_LDS16(g, l)                                                     \
    __builtin_amdgcn_global_load_lds(                                         \
        (const __attribute__((address_space(1))) void*)(const void*)(g),      \
        (__attribute__((address_space(3))) void*)(void*)(l), 16, 0, 0)

// ---------------- Weight prep: k[tap][cin][cout] f32 ->
// frag-order Wt[it][nsg][lane][8] bf16, it = tap*KS+ks, lane = sg*16+lr,
// cout = nsg*16+lr, cin = ks*32+sg*8+j.  16B per (it,nsg,lane) chunk.
template<int CIN, int COUT>
__device__ __forceinline__ void wprep_body(
    const float* __restrict__ k, unsigned short* __restrict__ wt, int blk)
{
    constexpr int NS = COUT / 16;
    constexpr int KS = CIN / 32;
    int idx = blk * 256 + (int)threadIdx.x;
    if (idx >= 27 * KS * NS * 64) return;
    int lane = idx & 63;
    int nsg  = (idx >> 6) % NS;
    int it   = idx / (64 * NS);
    int tap  = it / KS;
    int ks   = it - tap * KS;
    int sg = lane >> 4, lr = lane & 15;
    int cout = nsg * 16 + lr;
    ushort8v o;
    #pragma unroll
    for (int j = 0; j < 8; ++j) {
        int ci = ks * 32 + sg * 8 + j;
        o[j] = f2bf(k[(size_t)(tap * CIN + ci) * COUT + cout]);
    }
    *reinterpret_cast<ushort8v*>(wt + (size_t)idx * 8) = o;
}

__global__ __launch_bounds__(256) void wprep_all(
    const float* __restrict__ k1, const float* __restrict__ k2, const float* __restrict__ k3,
    unsigned short* __restrict__ w1, unsigned short* __restrict__ w2, unsigned short* __restrict__ w3,
    unsigned short* __restrict__ zp)
{
    int b = blockIdx.x;
    if (b < 27)       wprep_body<32, 64>(k1, w1, b);
    else if (b < 135) wprep_body<64, 128>(k2, w2, b - 27);
    else if (b < 567) wprep_body<128, 256>(k3, w3, b - 135);
    else {
        reinterpret_cast<unsigned int*>(zp)[threadIdx.x] = 0u;   // 1KB zero page
    }
}

// ---------------- Block 0: cin=1, cout=32, 96^3 -> 48^3 (fp32 in, bf16 out)
// v4: all 3 rows of a kd-slab loaded as one batch (15 independent loads),
// then a 576-FMA burst -> one latency stall per kd instead of three.
__global__ __launch_bounds__(256) void conv0_v4(
    const float* __restrict__ x, const float* __restrict__ k,
    const float* __restrict__ b, const float* __restrict__ g,
    const float* __restrict__ be, const float* __restrict__ m,
    const float* __restrict__ v, unsigned short* __restrict__ y)
{
    int t = blockIdx.x * 256 + threadIdx.x;
    int co8 = t & 3;  t >>= 2;
    int owq = t % 6;  t /= 6;
    int oh  = t % 48; t /= 48;
    int od  = t % 48; int n = t / 48;    // grid exact
    const int c0 = co8 * 8;

    float acc[8][8];
    #pragma unroll
    for (int q = 0; q < 8; ++q)
        #pragma unroll
        for (int j = 0; j < 8; ++j) acc[q][j] = 0.f;

    const int id0 = od * 2, ih0 = oh * 2, iwb = owq * 16;
    const bool wEdge = (owq == 5);

    #pragma unroll 1
    for (int kd = 0; kd < 3; ++kd) {
        const int id = id0 + kd;
        const bool dok = id < 96;
        float r[3][17];
        #pragma unroll
        for (int kh = 0; kh < 3; ++kh) {
            int ih = ih0 + kh;
            bool rok = dok && (ih < 96);
            const float* xr = x + ((size_t)(n * 96 + (rok ? id : 0)) * 96 + (rok ? ih : 0)) * 96 + iwb;
            float4 rA = f4load(xr);
            float4 rB = f4load(xr + 4);
            float4 rC = f4load(xr + 8);
            float4 rD = f4load(xr + 12);
            float r16 = xr[wEdge ? 15 : 16];
            r[kh][0] = rA.x;  r[kh][1] = rA.y;  r[kh][2] = rA.z;  r[kh][3] = rA.w;
            r[kh][4] = rB.x;  r[kh][5] = rB.y;  r[kh][6] = rB.z;  r[kh][7] = rB.w;
            r[kh][8] = rC.x;  r[kh][9] = rC.y;  r[kh][10] = rC.z; r[kh][11] = rC.w;
            r[kh][12] = rD.x; r[kh][13] = rD.y; r[kh][14] = rD.z; r[kh][15] = rD.w;
            r[kh][16] = wEdge ? 0.f : r16;
            if (!rok) {
                #pragma unroll
                for (int j = 0; j < 17; ++j) r[kh][j] = 0.f;
            }
        }
        #pragma unroll
        for (int kh = 0; kh < 3; ++kh) {
            #pragma unroll
            for (int kw = 0; kw < 3; ++kw) {
                const float* wp = k + ((kd * 3 + kh) * 3 + kw) * 32 + c0;
                float4 wA = f4load(wp), wB = f4load(wp + 4);
                float w8[8] = {wA.x, wA.y, wA.z, wA.w, wB.x, wB.y, wB.z, wB.w};
                #pragma unroll
                for (int q = 0; q < 8; ++q) {
                    float xv = r[kh][2 * q + kw];
                    #pragma unroll
                    for (int j = 0; j < 8; ++j) acc[q][j] += xv * w8[j];
                }
            }
        }
    }

    float S[8], T[8];
    #pragma unroll
    for (int j = 0; j < 8; ++j) {
        int c = c0 + j;
        float sc = g[c] * rsqrtf(v[c] + BN_EPS);
        S[j] = sc;
        T[j] = (b[c] - m[c]) * sc + be[c];
    }
    #pragma unroll
    for (int q = 0; q < 8; ++q) {
        int ow = owq * 8 + q;
        unsigned short* yp = y + (((size_t)(n * 48 + od) * 48 + oh) * 48 + ow) * 32 + c0;
        ushort8v o;
        #pragma unroll
        for (int j = 0; j < 8; ++j)
            o[j] = f2bf(fmaxf(acc[q][j] * S[j] + T[j], 0.f));
        *reinterpret_cast<ushort8v*>(yp) = o;
    }
}

// ---------------- MFMA implicit-GEMM conv, LDS double-buffered (m97 pattern).
// CSPLIT: grid-level cout split (more blocks for small-M layers).
// KU: K-steps staged per barrier iteration (amortizes barrier cost).
// B staged cooperatively by all 256 threads; A staged by ngroup==0 waves.
template<int CIN, int COUT, int INS, int OUTS, int MW, int NSW, int NH,
         int CSPLIT, int KU>
__global__ __launch_bounds__(256, 2) void conv_mfma_lds(
    const unsigned short* __restrict__ x, const unsigned short* __restrict__ wt,
    const unsigned short* __restrict__ zp,
    const float* __restrict__ b, const float* __restrict__ g,
    const float* __restrict__ be, const float* __restrict__ m,
    const float* __restrict__ v, unsigned short* __restrict__ y)
{
    constexpr int NSfull = COUT / 16;
    constexpr int NSB = NSW * NH;            // cout groups per block
    constexpr int KS = CIN / 32;
    constexpr int NITK = 27 * KS;
    constexpr int NIT = NITK / KU;
    constexpr int MGROUPS = 4 / NH;
    constexpr int MTILE = MGROUPS * MW * 16;
    constexpr int BSTEP = NSB * KU * 1024;
    constexpr int ASTEP = MGROUPS * MW * KU * 1024;
    constexpr int STRIDE = BSTEP + ASTEP;
    static_assert(NSB * CSPLIT == NSfull && NITK % KU == 0 && (NSB * KU) % 4 == 0, "tiling");

    __shared__ __attribute__((aligned(16))) char lds[2 * STRIDE];

    const int l   = threadIdx.x & 63;
    const int wid = threadIdx.x >> 6;
    const int sg  = l >> 4;
    const int lr  = l & 15;

    const int mblk   = blockIdx.x / CSPLIT;
    const int cchunk = blockIdx.x % CSPLIT;
    const int mgroup = wid / NH;
    const int ngroup = wid % NH;
    const int gCoutBase = (cchunk * NSB + ngroup * NSW) * 16;
    const int vwave = mblk * MTILE + mgroup * MW * 16;

    const unsigned short* ap0[MW];
    unsigned smask[MW];
    #pragma unroll
    for (int mi = 0; mi < MW; ++mi) {
        int vA = vwave + mi * 16 + lr;
        int owA = vA % OUTS; int t1 = vA / OUTS;
        int ohA = t1 % OUTS; int t2 = t1 / OUTS;
        int odA = t2 % OUTS; int nA = t2 / OUTS;
        ap0[mi] = x + ((((size_t)nA * INS + 2 * odA) * INS + 2 * ohA) * INS + 2 * owA) * CIN + sg * 8;
        smask[mi] = ((odA == OUTS - 1) ? 0x07FC0000u : 0u)
                  | ((ohA == OUTS - 1) ? 0x070381C0u : 0u)
                  | ((owA == OUTS - 1) ? 0x04924924u : 0u);
    }

    const unsigned short* zpl = (const unsigned short*)((const char*)zp + l * 16);

    f32x4 acc[MW][NSW];
    #pragma unroll
    for (int mi = 0; mi < MW; ++mi)
        #pragma unroll
        for (int ns = 0; ns < NSW; ++ns) acc[mi][ns] = (f32x4){0.f, 0.f, 0.f, 0.f};

    auto stage = [&](int ito, int p) {
        char* dst = &lds[p * STRIDE];
        // B: cooperative, 256 threads cover NSB*KU groups of 1KB
        #pragma unroll
        for (int c = 0; c < (NSB * KU) / 4; ++c) {
            int idx  = c * 256 + (int)threadIdx.x;
            int lane = idx & 63;
            int sub  = idx >> 6;                 // = u*NSB + grp
            int u    = sub / NSB;
            int grp  = sub % NSB;
            int it   = ito * KU + u;
            const unsigned short* src =
                wt + ((size_t)(it * NSfull + cchunk * NSB + grp) * 64 + lane) * 8;
            GLOAD_LDS16(src, dst + sub * 1024);
        }
        // A: staged by ngroup==0 waves for their mgroup
        if (ngroup == 0) {
            #pragma unroll
            for (int u = 0; u < KU; ++u) {
                int it = ito * KU + u;
                int tap = (KS == 1) ? it : it / KS;
                int ks  = (KS == 1) ? 0  : it - tap * KS;
                int kd = tap / 9, r9 = tap - kd * 9, kh = r9 / 3, kw = r9 - kh * 3;
                size_t aoff = (size_t)((kd * INS + kh) * INS + kw) * CIN + ks * 32;
                #pragma unroll
                for (int mi = 0; mi < MW; ++mi) {
                    const unsigned short* ga =
                        ((smask[mi] >> tap) & 1u) ? zpl : (ap0[mi] + aoff);
                    GLOAD_LDS16(ga, dst + BSTEP + ((mgroup * MW + mi) * KU + u) * 1024);
                }
            }
        }
    };

    stage(0, 0);
    __syncthreads();
    int cur = 0;
    #pragma unroll 1
    for (int ito = 0; ito < NIT; ++ito) {
        if (ito + 1 < NIT) stage(ito + 1, cur ^ 1);
        const char* buf = &lds[cur * STRIDE];
        #pragma unroll
        for (int u = 0; u < KU; ++u) {
            short8v Bf[NSW], Af[MW];
            #pragma unroll
            for (int ns = 0; ns < NSW; ++ns)
                Bf[ns] = *(const short8v*)(buf + (u * NSB + ngroup * NSW + ns) * 1024 + l * 16);
            #pragma unroll
            for (int mi = 0; mi < MW; ++mi)
                Af[mi] = *(const short8v*)(buf + BSTEP + ((mgroup * MW + mi) * KU + u) * 1024 + l * 16);
            #pragma unroll
            for (int mi = 0; mi < MW; ++mi)
                #pragma unroll
                for (int ns = 0; ns < NSW; ++ns)
                    acc[mi][ns] = __builtin_amdgcn_mfma_f32_16x16x32_bf16(Af[mi], Bf[ns], acc[mi][ns], 0, 0, 0);
        }
        __syncthreads();
        cur ^= 1;
    }

    float S[NSW], T[NSW];
    #pragma unroll
    for (int ns = 0; ns < NSW; ++ns) {
        int c = gCoutBase + ns * 16 + lr;
        float sc = g[c] * rsqrtf(v[c] + BN_EPS);
        S[ns] = sc;
        T[ns] = (b[c] - m[c]) * sc + be[c];
    }
    #pragma unroll
    for (int mi = 0; mi < MW; ++mi) {
        #pragma unroll
        for (int i = 0; i < 4; ++i) {
            int vD = vwave + mi * 16 + sg * 4 + i;
            int ow = vD % OUTS; int u1 = vD / OUTS;
            int oh = u1 % OUTS; int u2 = u1 / OUTS;
            int od = u2 % OUTS; int n = u2 / OUTS;
            unsigned short* yp =
                y + ((((size_t)n * OUTS + od) * OUTS + oh) * OUTS + ow) * COUT + gCoutBase + lr;
            #pragma unroll
            for (int ns = 0; ns < NSW; ++ns)
                yp[ns * 16] = f2bf(fmaxf(acc[mi][ns][i] * S[ns] + T[ns], 0.f));
        }
    }
}

// ---------------- Head: mean pool + 1x1 conv + BN/ReLU + 1x1 conv + top2 softmax
__global__ __launch_bounds__(256) void head_kernel(
    const unsigned short* __restrict__ x4,   // (16, 6,6,6, 256) bf16
    const float* __restrict__ w1k, const float* __restrict__ w1b,
    const float* __restrict__ wg,  const float* __restrict__ wbe,
    const float* __restrict__ wm,  const float* __restrict__ wv,
    const float* __restrict__ w2k, const float* __restrict__ w2b,
    float* __restrict__ out)
{
    __shared__ float part[8][256];
    __shared__ float h[256];
    __shared__ float r[256];
    __shared__ float logits[8];

    const int n = blockIdx.x;
    const int t = threadIdx.x;
    const int c8 = t & 31;
    const int pg = t >> 5;

    const unsigned short* xb = x4 + (size_t)n * 216 * 256 + c8 * 8;
    float s[8] = {0.f, 0.f, 0.f, 0.f, 0.f, 0.f, 0.f, 0.f};
    for (int i = pg; i < 216; i += 8) {
        ushort8v v8 = *reinterpret_cast<const ushort8v*>(xb + (size_t)i * 256);
        #pragma unroll
        for (int j = 0; j < 8; ++j) s[j] += bf2f(v8[j]);
    }
    #pragma unroll
    for (int j = 0; j < 8; ++j) part[pg][c8 * 8 + j] = s[j];
    __syncthreads();

    float a = 0.f;
    #pragma unroll
    for (int gi = 0; gi < 8; ++gi) a += part[gi][t];
    h[t] = a * (1.0f / 216.0f);
    __syncthreads();

    float acc = w1b[t];
    #pragma unroll 4
    for (int ci = 0; ci < 256; ++ci) acc += h[ci] * w1k[ci * 256 + t];
    float sc = wg[t] * rsqrtf(wv[t] + BN_EPS);
    acc = (acc - wm[t]) * sc + wbe[t];
    r[t] = fmaxf(acc, 0.f);
    __syncthreads();

    if (t < 8) {
        float a2 = w2b[t];
        for (int ci = 0; ci < 256; ++ci) a2 += r[ci] * w2k[ci * 8 + t];
        logits[t] = a2;
    }
    __syncthreads();

    if (t == 0) {
        float m1 = -INFINITY, m2 = -INFINITY;
        for (int e = 0; e < 8; ++e) {
            float val = logits[e];
            if (val > m1) { m2 = m1; m1 = val; }
            else if (val > m2) { m2 = val; }
        }
        float thr = m2;
        float ex[8]; float sum = 0.f;
        for (int e = 0; e < 8; ++e) {
            float val = (logits[e] >= thr) ? logits[e] : -INFINITY;
            ex[e] = expf(val - m1);
            sum += ex[e];
        }
        float inv = 1.0f / sum;
        for (int e = 0; e < 8; ++e) out[n * 8 + e] = ex[e] * inv;
    }
}

extern "C" void kernel_launch(void* const* d_in, const int* in_sizes, int n_in,
                              void* d_out, int out_size, void* d_ws, size_t ws_size,
                              hipStream_t stream) {
    const float* x   = (const float*)d_in[0];
    const float* k0  = (const float*)d_in[1];
    const float* b0  = (const float*)d_in[2];
    const float* g0  = (const float*)d_in[3];
    const float* be0 = (const float*)d_in[4];
    const float* m0  = (const float*)d_in[5];
    const float* v0  = (const float*)d_in[6];
    const float* k1  = (const float*)d_in[7];
    const float* b1  = (const float*)d_in[8];
    const float* g1  = (const float*)d_in[9];
    const float* be1 = (const float*)d_in[10];
    const float* m1  = (const float*)d_in[11];
    const float* v1  = (const float*)d_in[12];
    const float* k2  = (const float*)d_in[13];
    const float* b2  = (const float*)d_in[14];
    const float* g2  = (const float*)d_in[15];
    const float* be2 = (const float*)d_in[16];
    const float* m2  = (const float*)d_in[17];
    const float* v2  = (const float*)d_in[18];
    const float* k3  = (const float*)d_in[19];
    const float* b3  = (const float*)d_in[20];
    const float* g3  = (const float*)d_in[21];
    const float* be3 = (const float*)d_in[22];
    const float* m3  = (const float*)d_in[23];
    const float* v3  = (const float*)d_in[24];
    const float* w1k = (const float*)d_in[25];
    const float* w1b = (const float*)d_in[26];
    const float* wg  = (const float*)d_in[27];
    const float* wbe = (const float*)d_in[28];
    const float* wm  = (const float*)d_in[29];
    const float* wv  = (const float*)d_in[30];
    const float* w2k = (const float*)d_in[31];
    const float* w2b = (const float*)d_in[32];

    unsigned short* x1  = (unsigned short*)d_ws;
    unsigned short* x2  = x1 + 56623104;
    unsigned short* x3  = x2 + 14155776;
    unsigned short* x4  = x3 + 3538944;
    unsigned short* Wt1 = x4 + 884736;
    unsigned short* Wt2 = Wt1 + 55296;
    unsigned short* Wt3 = Wt2 + 221184;
    unsigned short* zp  = Wt3 + 884736;    // 1KB zero page

    wprep_all<<<568, 256, 0, stream>>>(k1, k2, k3, Wt1, Wt2, Wt3, zp);
    conv0_v4<<<3456, 256, 0, stream>>>(x, k0, b0, g0, be0, m0, v0, x1);
    // occupancy-retiled LDS-pipelined convs (R8 lesson: m97 structure works;
    // R5/R6 lesson: keep blocks >= ~3/CU):
    conv_mfma_lds<32, 64, 48, 24, 2, 4, 1, 1, 1><<<1728, 256, 0, stream>>>(x1, Wt1, zp, b1, g1, be1, m1, v1, x2);
    conv_mfma_lds<64, 128, 24, 12, 1, 4, 2, 1, 1><<<864, 256, 0, stream>>>(x2, Wt2, zp, b2, g2, be2, m2, v2, x3);
    conv_mfma_lds<128, 256, 12, 6, 1, 1, 4, 4, 2><<<864, 256, 0, stream>>>(x3, Wt3, zp, b3, g3, be3, m3, v3, x4);
    head_kernel<<<16, 256, 0, stream>>>(x4, w1k, w1b, wg, wbe, wm, wv, w2k, w2b, (float*)d_out);
}

// Round 10
// 213.164 us; speedup vs baseline: 1.7941x; 1.1651x over previous
//
#include <hip/hip_runtime.h>
#include <math.h>

#define BN_EPS 1e-3f

typedef __attribute__((ext_vector_type(8))) unsigned short ushort8v;
typedef __attribute__((ext_vector_type(8))) short short8v;
typedef __attribute__((ext_vector_type(4))) float f32x4;

__device__ __forceinline__ float4 f4load(const float* p) {
    return *reinterpret_cast<const float4*>(p);
}
__device__ __forceinline__ float bf2f(unsigned short u) {
    union { unsigned int i; float f; } w; w.i = ((unsigned int)u) << 16; return w.f;
}
__device__ __forceinline__ unsigned short f2bf(float f) {
    union { float fv; unsigned int i; } w; w.fv = f;
    unsigned int lsb = (w.i >> 16) & 1u;
    w.i += 0x7fffu + lsb;             // round-to-nearest-even
    return (unsigned short)(w.i >> 16);
}

#define GLOAD_LDS16(g, l)                                                     \
    __builtin_amdgcn_global_load_lds(                                         \
        (const __attribute__((address_space(1))) void*)(const void*)(g),      \
        (__attribute__((address_space(3))) void*)(void*)(l), 16, 0, 0)

// ---------------- Weight prep: k[tap][cin][cout] f32 ->
// frag-order Wt[it][nsg][lane][8] bf16 (see R8). Block 567 also builds the
// conv0 im2col B-table W0f[ns][lane][8] (K=27 taps padded to 32) + zero page.
template<int CIN, int COUT>
__device__ __forceinline__ void wprep_body(
    const float* __restrict__ k, unsigned short* __restrict__ wt, int blk)
{
    constexpr int NS = COUT / 16;
    constexpr int KS = CIN / 32;
    int idx = blk * 256 + (int)threadIdx.x;
    if (idx >= 27 * KS * NS * 64) return;
    int lane = idx & 63;
    int nsg  = (idx >> 6) % NS;
    int it   = idx / (64 * NS);
    int tap  = it / KS;
    int ks   = it - tap * KS;
    int sg = lane >> 4, lr = lane & 15;
    int cout = nsg * 16 + lr;
    ushort8v o;
    #pragma unroll
    for (int j = 0; j < 8; ++j) {
        int ci = ks * 32 + sg * 8 + j;
        o[j] = f2bf(k[(size_t)(tap * CIN + ci) * COUT + cout]);
    }
    *reinterpret_cast<ushort8v*>(wt + (size_t)idx * 8) = o;
}

__global__ __launch_bounds__(256) void wprep_all(
    const float* __restrict__ k0,
    const float* __restrict__ k1, const float* __restrict__ k2, const float* __restrict__ k3,
    unsigned short* __restrict__ w0f,
    unsigned short* __restrict__ w1, unsigned short* __restrict__ w2, unsigned short* __restrict__ w3,
    unsigned short* __restrict__ zp)
{
    int b = blockIdx.x;
    if (b < 27)       wprep_body<32, 64>(k1, w1, b);
    else if (b < 135) wprep_body<64, 128>(k2, w2, b - 27);
    else if (b < 567) wprep_body<128, 256>(k3, w3, b - 135);
    else {
        reinterpret_cast<unsigned int*>(zp)[threadIdx.x] = 0u;   // 1KB zero page
        if (threadIdx.x < 128) {
            int ns = threadIdx.x >> 6, lane = threadIdx.x & 63;
            int sg = lane >> 4, lr = lane & 15;
            ushort8v o;
            #pragma unroll
            for (int j = 0; j < 8; ++j) {
                int t = sg * 8 + j;
                o[j] = (t < 27) ? f2bf(k0[t * 32 + ns * 16 + lr]) : (unsigned short)0;
            }
            *reinterpret_cast<ushort8v*>(w0f + (ns * 64 + lane) * 8) = o;
        }
    }
}

// ---------------- Block 0 as im2col MFMA: K=27 taps (pad 32), N=32 couts.
// No LDS, no barriers: B-frags in 8 VGPRs, A gathered per-lane (8 scalar
// loads, masked taps -> zero page), 2 MFMAs per 16-voxel subtile.
__global__ __launch_bounds__(256) void conv0_mfma(
    const float* __restrict__ x, const unsigned short* __restrict__ w0f,
    const float* __restrict__ zf,
    const float* __restrict__ b, const float* __restrict__ g,
    const float* __restrict__ be, const float* __restrict__ m,
    const float* __restrict__ v, unsigned short* __restrict__ y)
{
    const int l   = threadIdx.x & 63;
    const int wid = threadIdx.x >> 6;
    const int sg  = l >> 4;
    const int lr  = l & 15;
    const int vwave = (blockIdx.x * 4 + wid) * 64;   // 4 M-subtiles/wave

    const short8v B0 = *(const short8v*)(w0f + l * 8);
    const short8v B1 = *(const short8v*)(w0f + (64 + l) * 8);

    // per-lane tap offsets for K-slots sg*8+j (constant over subtiles)
    int offs[8];
    #pragma unroll
    for (int j = 0; j < 8; ++j) {
        int t = sg * 8 + j;
        int kd = t / 9, r9 = t - kd * 9, kh = r9 / 3, kw = r9 - kh * 3;
        offs[j] = (kd * 96 + kh) * 96 + kw;
    }

    const float* ap0[4];
    unsigned m8[4];
    #pragma unroll
    for (int mi = 0; mi < 4; ++mi) {
        int vA = vwave + mi * 16 + lr;
        int ow = vA % 48; int t1 = vA / 48;
        int oh = t1 % 48; int t2 = t1 / 48;
        int od = t2 % 48; int n  = t2 / 48;
        ap0[mi] = x + ((size_t)(n * 96 + 2 * od) * 96 + 2 * oh) * 96 + 2 * ow;
        unsigned sm = ((od == 47) ? 0x07FC0000u : 0u)
                    | ((oh == 47) ? 0x070381C0u : 0u)
                    | ((ow == 47) ? 0x04924924u : 0u);
        m8[mi] = ((sm >> (sg * 8)) & 0xFFu) | ((sg == 3) ? 0xF8u : 0u);
    }

    // batch all 32 independent loads (branchless: masked -> zero page)
    float av[4][8];
    #pragma unroll
    for (int mi = 0; mi < 4; ++mi)
        #pragma unroll
        for (int j = 0; j < 8; ++j) {
            const float* p = ((m8[mi] >> j) & 1u) ? zf : (ap0[mi] + offs[j]);
            av[mi][j] = *p;
        }

    f32x4 acc[4][2];
    #pragma unroll
    for (int mi = 0; mi < 4; ++mi) {
        acc[mi][0] = (f32x4){0.f, 0.f, 0.f, 0.f};
        acc[mi][1] = (f32x4){0.f, 0.f, 0.f, 0.f};
    }
    #pragma unroll
    for (int mi = 0; mi < 4; ++mi) {
        short8v a;
        #pragma unroll
        for (int j = 0; j < 8; ++j) a[j] = (short)f2bf(av[mi][j]);
        acc[mi][0] = __builtin_amdgcn_mfma_f32_16x16x32_bf16(a, B0, acc[mi][0], 0, 0, 0);
        acc[mi][1] = __builtin_amdgcn_mfma_f32_16x16x32_bf16(a, B1, acc[mi][1], 0, 0, 0);
    }

    float S[2], T[2];
    #pragma unroll
    for (int ns = 0; ns < 2; ++ns) {
        int c = ns * 16 + lr;
        float sc = g[c] * rsqrtf(v[c] + BN_EPS);
        S[ns] = sc;
        T[ns] = (b[c] - m[c]) * sc + be[c];
    }
    #pragma unroll
    for (int mi = 0; mi < 4; ++mi) {
        #pragma unroll
        for (int i = 0; i < 4; ++i) {
            int vD = vwave + mi * 16 + sg * 4 + i;
            unsigned short* yp = y + (size_t)vD * 32;
            yp[lr]      = f2bf(fmaxf(acc[mi][0][i] * S[0] + T[0], 0.f));
            yp[16 + lr] = f2bf(fmaxf(acc[mi][1][i] * S[1] + T[1], 0.f));
        }
    }
}

// ---------------- MFMA implicit-GEMM conv, LDS double-buffered (m97 pattern).
template<int CIN, int COUT, int INS, int OUTS, int MW, int NSW, int NH,
         int CSPLIT, int KU>
__global__ __launch_bounds__(256, 2) void conv_mfma_lds(
    const unsigned short* __restrict__ x, const unsigned short* __restrict__ wt,
    const unsigned short* __restrict__ zp,
    const float* __restrict__ b, const float* __restrict__ g,
    const float* __restrict__ be, const float* __restrict__ m,
    const float* __restrict__ v, unsigned short* __restrict__ y)
{
    constexpr int NSfull = COUT / 16;
    constexpr int NSB = NSW * NH;
    constexpr int KS = CIN / 32;
    constexpr int NITK = 27 * KS;
    constexpr int NIT = NITK / KU;
    constexpr int MGROUPS = 4 / NH;
    constexpr int MTILE = MGROUPS * MW * 16;
    constexpr int BSTEP = NSB * KU * 1024;
    constexpr int ASTEP = MGROUPS * MW * KU * 1024;
    constexpr int STRIDE = BSTEP + ASTEP;
    static_assert(NSB * CSPLIT == NSfull && NITK % KU == 0 && (NSB * KU) % 4 == 0, "tiling");

    __shared__ __attribute__((aligned(16))) char lds[2 * STRIDE];

    const int l   = threadIdx.x & 63;
    const int wid = threadIdx.x >> 6;
    const int sg  = l >> 4;
    const int lr  = l & 15;

    const int mblk   = blockIdx.x / CSPLIT;
    const int cchunk = blockIdx.x % CSPLIT;
    const int mgroup = wid / NH;
    const int ngroup = wid % NH;
    const int gCoutBase = (cchunk * NSB + ngroup * NSW) * 16;
    const int vwave = mblk * MTILE + mgroup * MW * 16;

    const unsigned short* ap0[MW];
    unsigned smask[MW];
    #pragma unroll
    for (int mi = 0; mi < MW; ++mi) {
        int vA = vwave + mi * 16 + lr;
        int owA = vA % OUTS; int t1 = vA / OUTS;
        int ohA = t1 % OUTS; int t2 = t1 / OUTS;
        int odA = t2 % OUTS; int nA = t2 / OUTS;
        ap0[mi] = x + ((((size_t)nA * INS + 2 * odA) * INS + 2 * ohA) * INS + 2 * owA) * CIN + sg * 8;
        smask[mi] = ((odA == OUTS - 1) ? 0x07FC0000u : 0u)
                  | ((ohA == OUTS - 1) ? 0x070381C0u : 0u)
                  | ((owA == OUTS - 1) ? 0x04924924u : 0u);
    }

    const unsigned short* zpl = (const unsigned short*)((const char*)zp + l * 16);

    f32x4 acc[MW][NSW];
    #pragma unroll
    for (int mi = 0; mi < MW; ++mi)
        #pragma unroll
        for (int ns = 0; ns < NSW; ++ns) acc[mi][ns] = (f32x4){0.f, 0.f, 0.f, 0.f};

    auto stage = [&](int ito, int p) {
        char* dst = &lds[p * STRIDE];
        #pragma unroll
        for (int c = 0; c < (NSB * KU) / 4; ++c) {
            int idx  = c * 256 + (int)threadIdx.x;
            int lane = idx & 63;
            int sub  = idx >> 6;
            int u    = sub / NSB;
            int grp  = sub % NSB;
            int it   = ito * KU + u;
            const unsigned short* src =
                wt + ((size_t)(it * NSfull + cchunk * NSB + grp) * 64 + lane) * 8;
            GLOAD_LDS16(src, dst + sub * 1024);
        }
        if (ngroup == 0) {
            #pragma unroll
            for (int u = 0; u < KU; ++u) {
                int it = ito * KU + u;
                int tap = (KS == 1) ? it : it / KS;
                int ks  = (KS == 1) ? 0  : it - tap * KS;
                int kd = tap / 9, r9 = tap - kd * 9, kh = r9 / 3, kw = r9 - kh * 3;
                size_t aoff = (size_t)((kd * INS + kh) * INS + kw) * CIN + ks * 32;
                #pragma unroll
                for (int mi = 0; mi < MW; ++mi) {
                    const unsigned short* ga =
                        ((smask[mi] >> tap) & 1u) ? zpl : (ap0[mi] + aoff);
                    GLOAD_LDS16(ga, dst + BSTEP + ((mgroup * MW + mi) * KU + u) * 1024);
                }
            }
        }
    };

    stage(0, 0);
    __syncthreads();
    int cur = 0;
    #pragma unroll 1
    for (int ito = 0; ito < NIT; ++ito) {
        if (ito + 1 < NIT) stage(ito + 1, cur ^ 1);
        const char* buf = &lds[cur * STRIDE];
        #pragma unroll
        for (int u = 0; u < KU; ++u) {
            short8v Bf[NSW], Af[MW];
            #pragma unroll
            for (int ns = 0; ns < NSW; ++ns)
                Bf[ns] = *(const short8v*)(buf + (u * NSB + ngroup * NSW + ns) * 1024 + l * 16);
            #pragma unroll
            for (int mi = 0; mi < MW; ++mi)
                Af[mi] = *(const short8v*)(buf + BSTEP + ((mgroup * MW + mi) * KU + u) * 1024 + l * 16);
            #pragma unroll
            for (int mi = 0; mi < MW; ++mi)
                #pragma unroll
                for (int ns = 0; ns < NSW; ++ns)
                    acc[mi][ns] = __builtin_amdgcn_mfma_f32_16x16x32_bf16(Af[mi], Bf[ns], acc[mi][ns], 0, 0, 0);
        }
        __syncthreads();
        cur ^= 1;
    }

    float S[NSW], T[NSW];
    #pragma unroll
    for (int ns = 0; ns < NSW; ++ns) {
        int c = gCoutBase + ns * 16 + lr;
        float sc = g[c] * rsqrtf(v[c] + BN_EPS);
        S[ns] = sc;
        T[ns] = (b[c] - m[c]) * sc + be[c];
    }
    #pragma unroll
    for (int mi = 0; mi < MW; ++mi) {
        #pragma unroll
        for (int i = 0; i < 4; ++i) {
            int vD = vwave + mi * 16 + sg * 4 + i;
            int ow = vD % OUTS; int u1 = vD / OUTS;
            int oh = u1 % OUTS; int u2 = u1 / OUTS;
            int od = u2 % OUTS; int n = u2 / OUTS;
            unsigned short* yp =
                y + ((((size_t)n * OUTS + od) * OUTS + oh) * OUTS + ow) * COUT + gCoutBase + lr;
            #pragma unroll
            for (int ns = 0; ns < NSW; ++ns)
                yp[ns * 16] = f2bf(fmaxf(acc[mi][ns][i] * S[ns] + T[ns], 0.f));
        }
    }
}

// ---------------- Head: mean pool + 1x1 conv + BN/ReLU + 1x1 conv + top2 softmax
__global__ __launch_bounds__(256) void head_kernel(
    const unsigned short* __restrict__ x4,
    const float* __restrict__ w1k, const float* __restrict__ w1b,
    const float* __restrict__ wg,  const float* __restrict__ wbe,
    const float* __restrict__ wm,  const float* __restrict__ wv,
    const float* __restrict__ w2k, const float* __restrict__ w2b,
    float* __restrict__ out)
{
    __shared__ float part[8][256];
    __shared__ float h[256];
    __shared__ float r[256];
    __shared__ float logits[8];

    const int n = blockIdx.x;
    const int t = threadIdx.x;
    const int c8 = t & 31;
    const int pg = t >> 5;

    const unsigned short* xb = x4 + (size_t)n * 216 * 256 + c8 * 8;
    float s[8] = {0.f, 0.f, 0.f, 0.f, 0.f, 0.f, 0.f, 0.f};
    for (int i = pg; i < 216; i += 8) {
        ushort8v v8 = *reinterpret_cast<const ushort8v*>(xb + (size_t)i * 256);
        #pragma unroll
        for (int j = 0; j < 8; ++j) s[j] += bf2f(v8[j]);
    }
    #pragma unroll
    for (int j = 0; j < 8; ++j) part[pg][c8 * 8 + j] = s[j];
    __syncthreads();

    float a = 0.f;
    #pragma unroll
    for (int gi = 0; gi < 8; ++gi) a += part[gi][t];
    h[t] = a * (1.0f / 216.0f);
    __syncthreads();

    float acc = w1b[t];
    #pragma unroll 4
    for (int ci = 0; ci < 256; ++ci) acc += h[ci] * w1k[ci * 256 + t];
    float sc = wg[t] * rsqrtf(wv[t] + BN_EPS);
    acc = (acc - wm[t]) * sc + wbe[t];
    r[t] = fmaxf(acc, 0.f);
    __syncthreads();

    if (t < 8) {
        float a2 = w2b[t];
        for (int ci = 0; ci < 256; ++ci) a2 += r[ci] * w2k[ci * 8 + t];
        logits[t] = a2;
    }
    __syncthreads();

    if (t == 0) {
        float m1 = -INFINITY, m2 = -INFINITY;
        for (int e = 0; e < 8; ++e) {
            float val = logits[e];
            if (val > m1) { m2 = m1; m1 = val; }
            else if (val > m2) { m2 = val; }
        }
        float thr = m2;
        float ex[8]; float sum = 0.f;
        for (int e = 0; e < 8; ++e) {
            float val = (logits[e] >= thr) ? logits[e] : -INFINITY;
            ex[e] = expf(val - m1);
            sum += ex[e];
        }
        float inv = 1.0f / sum;
        for (int e = 0; e < 8; ++e) out[n * 8 + e] = ex[e] * inv;
    }
}

extern "C" void kernel_launch(void* const* d_in, const int* in_sizes, int n_in,
                              void* d_out, int out_size, void* d_ws, size_t ws_size,
                              hipStream_t stream) {
    const float* x   = (const float*)d_in[0];
    const float* k0  = (const float*)d_in[1];
    const float* b0  = (const float*)d_in[2];
    const float* g0  = (const float*)d_in[3];
    const float* be0 = (const float*)d_in[4];
    const float* m0  = (const float*)d_in[5];
    const float* v0  = (const float*)d_in[6];
    const float* k1  = (const float*)d_in[7];
    const float* b1  = (const float*)d_in[8];
    const float* g1  = (const float*)d_in[9];
    const float* be1 = (const float*)d_in[10];
    const float* m1  = (const float*)d_in[11];
    const float* v1  = (const float*)d_in[12];
    const float* k2  = (const float*)d_in[13];
    const float* b2  = (const float*)d_in[14];
    const float* g2  = (const float*)d_in[15];
    const float* be2 = (const float*)d_in[16];
    const float* m2  = (const float*)d_in[17];
    const float* v2  = (const float*)d_in[18];
    const float* k3  = (const float*)d_in[19];
    const float* b3  = (const float*)d_in[20];
    const float* g3  = (const float*)d_in[21];
    const float* be3 = (const float*)d_in[22];
    const float* m3  = (const float*)d_in[23];
    const float* v3  = (const float*)d_in[24];
    const float* w1k = (const float*)d_in[25];
    const float* w1b = (const float*)d_in[26];
    const float* wg  = (const float*)d_in[27];
    const float* wbe = (const float*)d_in[28];
    const float* wm  = (const float*)d_in[29];
    const float* wv  = (const float*)d_in[30];
    const float* w2k = (const float*)d_in[31];
    const float* w2b = (const float*)d_in[32];

    unsigned short* x1  = (unsigned short*)d_ws;
    unsigned short* x2  = x1 + 56623104;
    unsigned short* x3  = x2 + 14155776;
    unsigned short* x4  = x3 + 3538944;
    unsigned short* Wt1 = x4 + 884736;
    unsigned short* Wt2 = Wt1 + 55296;
    unsigned short* Wt3 = Wt2 + 221184;
    unsigned short* zp  = Wt3 + 884736;    // 1KB zero page
    unsigned short* W0f = zp + 512;        // conv0 im2col B table (2KB)

    wprep_all<<<568, 256, 0, stream>>>(k0, k1, k2, k3, W0f, Wt1, Wt2, Wt3, zp);
    conv0_mfma<<<6912, 256, 0, stream>>>(x, W0f, (const float*)zp, b0, g0, be0, m0, v0, x1);
    conv_mfma_lds<32, 64, 48, 24, 2, 4, 1, 1, 1><<<1728, 256, 0, stream>>>(x1, Wt1, zp, b1, g1, be1, m1, v1, x2);
    conv_mfma_lds<64, 128, 24, 12, 1, 4, 2, 1, 1><<<864, 256, 0, stream>>>(x2, Wt2, zp, b2, g2, be2, m2, v2, x3);
    conv_mfma_lds<128, 256, 12, 6, 1, 1, 4, 4, 2><<<864, 256, 0, stream>>>(x3, Wt3, zp, b3, g3, be3, m3, v3, x4);
    head_kernel<<<16, 256, 0, stream>>>(x4, w1k, w1b, wg, wbe, wm, wv, w2k, w2b, (float*)d_out);
}

// Round 11
// 199.778 us; speedup vs baseline: 1.9143x; 1.0670x over previous
//
#include <hip/hip_runtime.h>
#include <math.h>

#define BN_EPS 1e-3f

typedef __attribute__((ext_vector_type(8))) unsigned short ushort8v;
typedef __attribute__((ext_vector_type(8))) short short8v;
typedef __attribute__((ext_vector_type(4))) float f32x4;
typedef __attribute__((ext_vector_type(4))) unsigned int uint4v;

__device__ __forceinline__ float4 f4load(const float* p) {
    return *reinterpret_cast<const float4*>(p);
}
__device__ __forceinline__ float bf2f(unsigned short u) {
    union { unsigned int i; float f; } w; w.i = ((unsigned int)u) << 16; return w.f;
}
__device__ __forceinline__ unsigned short f2bf(float f) {
    union { float fv; unsigned int i; } w; w.fv = f;
    unsigned int lsb = (w.i >> 16) & 1u;
    w.i += 0x7fffu + lsb;             // round-to-nearest-even
    return (unsigned short)(w.i >> 16);
}
// HW packed convert: returns [bf16(hi)<<16 | bf16(lo)]  (T12 recipe, RTNE)
__device__ __forceinline__ unsigned cvtpk(float lo, float hi) {
    unsigned r;
    asm("v_cvt_pk_bf16_f32 %0, %1, %2" : "=v"(r) : "v"(lo), "v"(hi));
    return r;
}
__device__ __forceinline__ void st_pair(unsigned short* p0, unsigned short* p1,
                                        float f0, float f1) {
    unsigned u = cvtpk(f0, f1);
    p0[0] = (unsigned short)u;
    p1[0] = (unsigned short)(u >> 16);
}
template<int N> __device__ __forceinline__ void waitv() {
    asm volatile("s_waitcnt vmcnt(%0)" :: "n"(N) : "memory");
}

#define GLOAD_LDS16(g, l)                                                     \
    __builtin_amdgcn_global_load_lds(                                         \
        (const __attribute__((address_space(1))) void*)(const void*)(g),      \
        (__attribute__((address_space(3))) void*)(void*)(l), 16, 0, 0)

// ---------------- Weight prep: k[tap][cin][cout] f32 ->
// frag-order Wt[it][nsg][lane][8] bf16; block 567 builds conv0 B-table + zero page.
template<int CIN, int COUT>
__device__ __forceinline__ void wprep_body(
    const float* __restrict__ k, unsigned short* __restrict__ wt, int blk)
{
    constexpr int NS = COUT / 16;
    constexpr int KS = CIN / 32;
    int idx = blk * 256 + (int)threadIdx.x;
    if (idx >= 27 * KS * NS * 64) return;
    int lane = idx & 63;
    int nsg  = (idx >> 6) % NS;
    int it   = idx / (64 * NS);
    int tap  = it / KS;
    int ks   = it - tap * KS;
    int sg = lane >> 4, lr = lane & 15;
    int cout = nsg * 16 + lr;
    ushort8v o;
    #pragma unroll
    for (int j = 0; j < 8; ++j) {
        int ci = ks * 32 + sg * 8 + j;
        o[j] = f2bf(k[(size_t)(tap * CIN + ci) * COUT + cout]);
    }
    *reinterpret_cast<ushort8v*>(wt + (size_t)idx * 8) = o;
}

__global__ __launch_bounds__(256) void wprep_all(
    const float* __restrict__ k0,
    const float* __restrict__ k1, const float* __restrict__ k2, const float* __restrict__ k3,
    unsigned short* __restrict__ w0f,
    unsigned short* __restrict__ w1, unsigned short* __restrict__ w2, unsigned short* __restrict__ w3,
    unsigned short* __restrict__ zp)
{
    int b = blockIdx.x;
    if (b < 27)       wprep_body<32, 64>(k1, w1, b);
    else if (b < 135) wprep_body<64, 128>(k2, w2, b - 27);
    else if (b < 567) wprep_body<128, 256>(k3, w3, b - 135);
    else {
        reinterpret_cast<unsigned int*>(zp)[threadIdx.x] = 0u;   // 1KB zero page
        if (threadIdx.x < 128) {
            int ns = threadIdx.x >> 6, lane = threadIdx.x & 63;
            int sg = lane >> 4, lr = lane & 15;
            ushort8v o;
            #pragma unroll
            for (int j = 0; j < 8; ++j) {
                int t = sg * 8 + j;
                o[j] = (t < 27) ? f2bf(k0[t * 32 + ns * 16 + lr]) : (unsigned short)0;
            }
            *reinterpret_cast<ushort8v*>(w0f + (ns * 64 + lane) * 8) = o;
        }
    }
}

// ---------------- Block 0 as im2col MFMA: K=27 taps (pad 32), N=32 couts.
__global__ __launch_bounds__(256) void conv0_mfma(
    const float* __restrict__ x, const unsigned short* __restrict__ w0f,
    const float* __restrict__ zf,
    const float* __restrict__ b, const float* __restrict__ g,
    const float* __restrict__ be, const float* __restrict__ m,
    const float* __restrict__ v, unsigned short* __restrict__ y)
{
    const int l   = threadIdx.x & 63;
    const int wid = threadIdx.x >> 6;
    const int sg  = l >> 4;
    const int lr  = l & 15;
    const int vwave = (blockIdx.x * 4 + wid) * 64;   // 4 M-subtiles/wave

    const short8v B0 = *(const short8v*)(w0f + l * 8);
    const short8v B1 = *(const short8v*)(w0f + (64 + l) * 8);

    int offs[8];
    #pragma unroll
    for (int j = 0; j < 8; ++j) {
        int t = sg * 8 + j;
        int kd = t / 9, r9 = t - kd * 9, kh = r9 / 3, kw = r9 - kh * 3;
        offs[j] = (kd * 96 + kh) * 96 + kw;
    }

    const float* ap0[4];
    unsigned m8[4];
    #pragma unroll
    for (int mi = 0; mi < 4; ++mi) {
        int vA = vwave + mi * 16 + lr;
        int ow = vA % 48; int t1 = vA / 48;
        int oh = t1 % 48; int t2 = t1 / 48;
        int od = t2 % 48; int n  = t2 / 48;
        ap0[mi] = x + ((size_t)(n * 96 + 2 * od) * 96 + 2 * oh) * 96 + 2 * ow;
        unsigned sm = ((od == 47) ? 0x07FC0000u : 0u)
                    | ((oh == 47) ? 0x070381C0u : 0u)
                    | ((ow == 47) ? 0x04924924u : 0u);
        m8[mi] = ((sm >> (sg * 8)) & 0xFFu) | ((sg == 3) ? 0xF8u : 0u);
    }

    float av[4][8];
    #pragma unroll
    for (int mi = 0; mi < 4; ++mi)
        #pragma unroll
        for (int j = 0; j < 8; ++j) {
            const float* p = ((m8[mi] >> j) & 1u) ? zf : (ap0[mi] + offs[j]);
            av[mi][j] = *p;
        }

    f32x4 acc[4][2];
    #pragma unroll
    for (int mi = 0; mi < 4; ++mi) {
        acc[mi][0] = (f32x4){0.f, 0.f, 0.f, 0.f};
        acc[mi][1] = (f32x4){0.f, 0.f, 0.f, 0.f};
    }
    #pragma unroll
    for (int mi = 0; mi < 4; ++mi) {
        uint4v au;
        au[0] = cvtpk(av[mi][0], av[mi][1]);
        au[1] = cvtpk(av[mi][2], av[mi][3]);
        au[2] = cvtpk(av[mi][4], av[mi][5]);
        au[3] = cvtpk(av[mi][6], av[mi][7]);
        short8v a = __builtin_bit_cast(short8v, au);
        acc[mi][0] = __builtin_amdgcn_mfma_f32_16x16x32_bf16(a, B0, acc[mi][0], 0, 0, 0);
        acc[mi][1] = __builtin_amdgcn_mfma_f32_16x16x32_bf16(a, B1, acc[mi][1], 0, 0, 0);
    }

    float S[2], T[2];
    #pragma unroll
    for (int ns = 0; ns < 2; ++ns) {
        int c = ns * 16 + lr;
        float sc = g[c] * rsqrtf(v[c] + BN_EPS);
        S[ns] = sc;
        T[ns] = (b[c] - m[c]) * sc + be[c];
    }
    #pragma unroll
    for (int mi = 0; mi < 4; ++mi) {
        #pragma unroll
        for (int i = 0; i < 4; i += 2) {
            int vD0 = vwave + mi * 16 + sg * 4 + i;
            unsigned short* yp0 = y + (size_t)vD0 * 32;
            unsigned short* yp1 = yp0 + 32;
            st_pair(yp0 + lr, yp1 + lr,
                    fmaxf(acc[mi][0][i]     * S[0] + T[0], 0.f),
                    fmaxf(acc[mi][0][i + 1] * S[0] + T[0], 0.f));
            st_pair(yp0 + 16 + lr, yp1 + 16 + lr,
                    fmaxf(acc[mi][1][i]     * S[1] + T[1], 0.f),
                    fmaxf(acc[mi][1][i + 1] * S[1] + T[1], 0.f));
        }
    }
}

// ---------------- MFMA implicit-GEMM conv: 3-buffer depth-2 pipeline,
// counted vmcnt + raw s_barrier (T3/T4; never vmcnt(0) in main loop).
template<int CIN, int COUT, int INS, int OUTS, int MW, int NSW, int NH,
         int CSPLIT, int KU>
__global__ __launch_bounds__(256, 2) void conv_mfma_lds(
    const unsigned short* __restrict__ x, const unsigned short* __restrict__ wt,
    const unsigned short* __restrict__ zp,
    const float* __restrict__ b, const float* __restrict__ g,
    const float* __restrict__ be, const float* __restrict__ m,
    const float* __restrict__ v, unsigned short* __restrict__ y)
{
    constexpr int NSfull = COUT / 16;
    constexpr int NSB = NSW * NH;
    constexpr int KS = CIN / 32;
    constexpr int NITK = 27 * KS;
    constexpr int NIT = NITK / KU;
    constexpr int MGROUPS = 4 / NH;
    constexpr int MTILE = MGROUPS * MW * 16;
    constexpr int BSTEP = NSB * KU * 1024;
    constexpr int ASTEP = MGROUPS * MW * KU * 1024;
    constexpr int STRIDE = BSTEP + ASTEP;
    constexpr int BL = (NSB * KU) / 4;       // B loads per thread per stage
    constexpr int AL = MW * KU;              // A loads per thread (ngroup==0 waves)
    static_assert(NSB * CSPLIT == NSfull && NITK % KU == 0 && (NSB * KU) % 4 == 0, "tiling");
    static_assert(NIT >= 3, "pipeline depth");

    __shared__ __attribute__((aligned(16))) char lds[3 * STRIDE];

    const int l   = threadIdx.x & 63;
    const int wid = threadIdx.x >> 6;
    const int sg  = l >> 4;
    const int lr  = l & 15;

    const int mblk   = blockIdx.x / CSPLIT;
    const int cchunk = blockIdx.x % CSPLIT;
    const int mgroup = wid / NH;
    const int ngroup = wid % NH;
    const int gCoutBase = (cchunk * NSB + ngroup * NSW) * 16;
    const int vwave = mblk * MTILE + mgroup * MW * 16;

    const unsigned short* ap0[MW];
    unsigned smask[MW];
    #pragma unroll
    for (int mi = 0; mi < MW; ++mi) {
        int vA = vwave + mi * 16 + lr;
        int owA = vA % OUTS; int t1 = vA / OUTS;
        int ohA = t1 % OUTS; int t2 = t1 / OUTS;
        int odA = t2 % OUTS; int nA = t2 / OUTS;
        ap0[mi] = x + ((((size_t)nA * INS + 2 * odA) * INS + 2 * ohA) * INS + 2 * owA) * CIN + sg * 8;
        smask[mi] = ((odA == OUTS - 1) ? 0x07FC0000u : 0u)
                  | ((ohA == OUTS - 1) ? 0x070381C0u : 0u)
                  | ((owA == OUTS - 1) ? 0x04924924u : 0u);
    }

    const unsigned short* zpl = (const unsigned short*)((const char*)zp + l * 16);

    f32x4 acc[MW][NSW];
    #pragma unroll
    for (int mi = 0; mi < MW; ++mi)
        #pragma unroll
        for (int ns = 0; ns < NSW; ++ns) acc[mi][ns] = (f32x4){0.f, 0.f, 0.f, 0.f};

    auto stage = [&](int ito, int p) {
        char* dst = &lds[p * STRIDE];
        #pragma unroll
        for (int c = 0; c < BL; ++c) {
            int idx  = c * 256 + (int)threadIdx.x;
            int lane = idx & 63;
            int sub  = idx >> 6;
            int u    = sub / NSB;
            int grp  = sub % NSB;
            int it   = ito * KU + u;
            const unsigned short* src =
                wt + ((size_t)(it * NSfull + cchunk * NSB + grp) * 64 + lane) * 8;
            GLOAD_LDS16(src, dst + sub * 1024);
        }
        if (ngroup == 0) {
            #pragma unroll
            for (int u = 0; u < KU; ++u) {
                int it = ito * KU + u;
                int tap = (KS == 1) ? it : it / KS;
                int ks  = (KS == 1) ? 0  : it - tap * KS;
                int kd = tap / 9, r9 = tap - kd * 9, kh = r9 / 3, kw = r9 - kh * 3;
                size_t aoff = (size_t)((kd * INS + kh) * INS + kw) * CIN + ks * 32;
                #pragma unroll
                for (int mi = 0; mi < MW; ++mi) {
                    const unsigned short* ga =
                        ((smask[mi] >> tap) & 1u) ? zpl : (ap0[mi] + aoff);
                    GLOAD_LDS16(ga, dst + BSTEP + ((mgroup * MW + mi) * KU + u) * 1024);
                }
            }
        }
    };

    auto computestep = [&](const char* buf) {
        #pragma unroll
        for (int u = 0; u < KU; ++u) {
            short8v Bf[NSW], Af[MW];
            #pragma unroll
            for (int ns = 0; ns < NSW; ++ns)
                Bf[ns] = *(const short8v*)(buf + (u * NSB + ngroup * NSW + ns) * 1024 + l * 16);
            #pragma unroll
            for (int mi = 0; mi < MW; ++mi)
                Af[mi] = *(const short8v*)(buf + BSTEP + ((mgroup * MW + mi) * KU + u) * 1024 + l * 16);
            #pragma unroll
            for (int mi = 0; mi < MW; ++mi)
                #pragma unroll
                for (int ns = 0; ns < NSW; ++ns)
                    acc[mi][ns] = __builtin_amdgcn_mfma_f32_16x16x32_bf16(Af[mi], Bf[ns], acc[mi][ns], 0, 0, 0);
        }
    };

    stage(0, 0);
    stage(1, 1);
    #pragma unroll 1
    for (int ito = 0; ito < NIT - 1; ++ito) {
        // wait my stage(ito); stage(ito+1) stays in flight
        if (ngroup == 0) waitv<BL + AL>(); else waitv<BL>();
        __builtin_amdgcn_s_barrier();
        asm volatile("" ::: "memory");
        if (ito + 2 < NIT) stage(ito + 2, (ito + 2) % 3);
        computestep(&lds[(ito % 3) * STRIDE]);
    }
    waitv<0>();
    __builtin_amdgcn_s_barrier();
    asm volatile("" ::: "memory");
    computestep(&lds[((NIT - 1) % 3) * STRIDE]);

    float S[NSW], T[NSW];
    #pragma unroll
    for (int ns = 0; ns < NSW; ++ns) {
        int c = gCoutBase + ns * 16 + lr;
        float sc = g[c] * rsqrtf(v[c] + BN_EPS);
        S[ns] = sc;
        T[ns] = (b[c] - m[c]) * sc + be[c];
    }
    #pragma unroll
    for (int mi = 0; mi < MW; ++mi) {
        #pragma unroll
        for (int i = 0; i < 4; i += 2) {
            int vD0 = vwave + mi * 16 + sg * 4 + i;
            int vD1 = vD0 + 1;
            int ow0 = vD0 % OUTS; int u1 = vD0 / OUTS;
            int oh0 = u1 % OUTS; int u2 = u1 / OUTS;
            int od0 = u2 % OUTS; int n0 = u2 / OUTS;
            unsigned short* yp0 =
                y + ((((size_t)n0 * OUTS + od0) * OUTS + oh0) * OUTS + ow0) * COUT + gCoutBase + lr;
            int ow1 = vD1 % OUTS; int w1 = vD1 / OUTS;
            int oh1 = w1 % OUTS; int w2 = w1 / OUTS;
            int od1 = w2 % OUTS; int n1 = w2 / OUTS;
            unsigned short* yp1 =
                y + ((((size_t)n1 * OUTS + od1) * OUTS + oh1) * OUTS + ow1) * COUT + gCoutBase + lr;
            #pragma unroll
            for (int ns = 0; ns < NSW; ++ns)
                st_pair(yp0 + ns * 16, yp1 + ns * 16,
                        fmaxf(acc[mi][ns][i]     * S[ns] + T[ns], 0.f),
                        fmaxf(acc[mi][ns][i + 1] * S[ns] + T[ns], 0.f));
        }
    }
}

// ---------------- Head: mean pool + 1x1 conv + BN/ReLU + 1x1 conv + top2 softmax
__global__ __launch_bounds__(256) void head_kernel(
    const unsigned short* __restrict__ x4,
    const float* __restrict__ w1k, const float* __restrict__ w1b,
    const float* __restrict__ wg,  const float* __restrict__ wbe,
    const float* __restrict__ wm,  const float* __restrict__ wv,
    const float* __restrict__ w2k, const float* __restrict__ w2b,
    float* __restrict__ out)
{
    __shared__ float part[8][256];
    __shared__ float h[256];
    __shared__ float r[256];
    __shared__ float logits[8];

    const int n = blockIdx.x;
    const int t = threadIdx.x;
    const int c8 = t & 31;
    const int pg = t >> 5;

    const unsigned short* xb = x4 + (size_t)n * 216 * 256 + c8 * 8;
    float s[8] = {0.f, 0.f, 0.f, 0.f, 0.f, 0.f, 0.f, 0.f};
    for (int i = pg; i < 216; i += 8) {
        ushort8v v8 = *reinterpret_cast<const ushort8v*>(xb + (size_t)i * 256);
        #pragma unroll
        for (int j = 0; j < 8; ++j) s[j] += bf2f(v8[j]);
    }
    #pragma unroll
    for (int j = 0; j < 8; ++j) part[pg][c8 * 8 + j] = s[j];
    __syncthreads();

    float a = 0.f;
    #pragma unroll
    for (int gi = 0; gi < 8; ++gi) a += part[gi][t];
    h[t] = a * (1.0f / 216.0f);
    __syncthreads();

    float acc = w1b[t];
    #pragma unroll 4
    for (int ci = 0; ci < 256; ++ci) acc += h[ci] * w1k[ci * 256 + t];
    float sc = wg[t] * rsqrtf(wv[t] + BN_EPS);
    acc = (acc - wm[t]) * sc + wbe[t];
    r[t] = fmaxf(acc, 0.f);
    __syncthreads();

    if (t < 8) {
        float a2 = w2b[t];
        for (int ci = 0; ci < 256; ++ci) a2 += r[ci] * w2k[ci * 8 + t];
        logits[t] = a2;
    }
    __syncthreads();

    if (t == 0) {
        float m1 = -INFINITY, m2 = -INFINITY;
        for (int e = 0; e < 8; ++e) {
            float val = logits[e];
            if (val > m1) { m2 = m1; m1 = val; }
            else if (val > m2) { m2 = val; }
        }
        float thr = m2;
        float ex[8]; float sum = 0.f;
        for (int e = 0; e < 8; ++e) {
            float val = (logits[e] >= thr) ? logits[e] : -INFINITY;
            ex[e] = expf(val - m1);
            sum += ex[e];
        }
        float inv = 1.0f / sum;
        for (int e = 0; e < 8; ++e) out[n * 8 + e] = ex[e] * inv;
    }
}

extern "C" void kernel_launch(void* const* d_in, const int* in_sizes, int n_in,
                              void* d_out, int out_size, void* d_ws, size_t ws_size,
                              hipStream_t stream) {
    const float* x   = (const float*)d_in[0];
    const float* k0  = (const float*)d_in[1];
    const float* b0  = (const float*)d_in[2];
    const float* g0  = (const float*)d_in[3];
    const float* be0 = (const float*)d_in[4];
    const float* m0  = (const float*)d_in[5];
    const float* v0  = (const float*)d_in[6];
    const float* k1  = (const float*)d_in[7];
    const float* b1  = (const float*)d_in[8];
    const float* g1  = (const float*)d_in[9];
    const float* be1 = (const float*)d_in[10];
    const float* m1  = (const float*)d_in[11];
    const float* v1  = (const float*)d_in[12];
    const float* k2  = (const float*)d_in[13];
    const float* b2  = (const float*)d_in[14];
    const float* g2  = (const float*)d_in[15];
    const float* be2 = (const float*)d_in[16];
    const float* m2  = (const float*)d_in[17];
    const float* v2  = (const float*)d_in[18];
    const float* k3  = (const float*)d_in[19];
    const float* b3  = (const float*)d_in[20];
    const float* g3  = (const float*)d_in[21];
    const float* be3 = (const float*)d_in[22];
    const float* m3  = (const float*)d_in[23];
    const float* v3  = (const float*)d_in[24];
    const float* w1k = (const float*)d_in[25];
    const float* w1b = (const float*)d_in[26];
    const float* wg  = (const float*)d_in[27];
    const float* wbe = (const float*)d_in[28];
    const float* wm  = (const float*)d_in[29];
    const float* wv  = (const float*)d_in[30];
    const float* w2k = (const float*)d_in[31];
    const float* w2b = (const float*)d_in[32];

    unsigned short* x1  = (unsigned short*)d_ws;
    unsigned short* x2  = x1 + 56623104;
    unsigned short* x3  = x2 + 14155776;
    unsigned short* x4  = x3 + 3538944;
    unsigned short* Wt1 = x4 + 884736;
    unsigned short* Wt2 = Wt1 + 55296;
    unsigned short* Wt3 = Wt2 + 221184;
    unsigned short* zp  = Wt3 + 884736;    // 1KB zero page
    unsigned short* W0f = zp + 512;        // conv0 im2col B table (2KB)

    wprep_all<<<568, 256, 0, stream>>>(k0, k1, k2, k3, W0f, Wt1, Wt2, Wt3, zp);
    conv0_mfma<<<6912, 256, 0, stream>>>(x, W0f, (const float*)zp, b0, g0, be0, m0, v0, x1);
    conv_mfma_lds<32, 64, 48, 24, 2, 4, 1, 1, 1><<<1728, 256, 0, stream>>>(x1, Wt1, zp, b1, g1, be1, m1, v1, x2);
    conv_mfma_lds<64, 128, 24, 12, 1, 4, 2, 1, 1><<<864, 256, 0, stream>>>(x2, Wt2, zp, b2, g2, be2, m2, v2, x3);
    conv_mfma_lds<128, 256, 12, 6, 1, 1, 4, 4, 2><<<864, 256, 0, stream>>>(x3, Wt3, zp, b3, g3, be3, m3, v3, x4);
    head_kernel<<<16, 256, 0, stream>>>(x4, w1k, w1b, wg, wbe, wm, wv, w2k, w2b, (float*)d_out);
}

// Round 12
// 195.802 us; speedup vs baseline: 1.9532x; 1.0203x over previous
//
#include <hip/hip_runtime.h>
#include <math.h>

#define BN_EPS 1e-3f

typedef __attribute__((ext_vector_type(8))) unsigned short ushort8v;
typedef __attribute__((ext_vector_type(8))) short short8v;
typedef __attribute__((ext_vector_type(4))) float f32x4;
typedef __attribute__((ext_vector_type(4))) unsigned int uint4v;

__device__ __forceinline__ float4 f4load(const float* p) {
    return *reinterpret_cast<const float4*>(p);
}
__device__ __forceinline__ float bf2f(unsigned short u) {
    union { unsigned int i; float f; } w; w.i = ((unsigned int)u) << 16; return w.f;
}
__device__ __forceinline__ unsigned short f2bf(float f) {
    union { float fv; unsigned int i; } w; w.fv = f;
    unsigned int lsb = (w.i >> 16) & 1u;
    w.i += 0x7fffu + lsb;             // round-to-nearest-even
    return (unsigned short)(w.i >> 16);
}
// HW packed convert: returns [bf16(hi)<<16 | bf16(lo)] (RTNE)
__device__ __forceinline__ unsigned cvtpk(float lo, float hi) {
    unsigned r;
    asm("v_cvt_pk_bf16_f32 %0, %1, %2" : "=v"(r) : "v"(lo), "v"(hi));
    return r;
}
__device__ __forceinline__ void st_pair(unsigned short* p0, unsigned short* p1,
                                        float f0, float f1) {
    unsigned u = cvtpk(f0, f1);
    p0[0] = (unsigned short)u;
    p1[0] = (unsigned short)(u >> 16);
}
template<int N> __device__ __forceinline__ void waitv() {
    asm volatile("s_waitcnt vmcnt(%0)" :: "n"(N) : "memory");
}

#define GLOAD_LDS16(g, l)                                                     \
    __builtin_amdgcn_global_load_lds(                                         \
        (const __attribute__((address_space(1))) void*)(const void*)(g),      \
        (__attribute__((address_space(3))) void*)(void*)(l), 16, 0, 0)
#define GLOAD_LDS4(g, l)                                                      \
    __builtin_amdgcn_global_load_lds(                                         \
        (const __attribute__((address_space(1))) void*)(const void*)(g),      \
        (__attribute__((address_space(3))) void*)(void*)(l), 4, 0, 0)

// ---------------- Weight prep: k[tap][cin][cout] f32 ->
// frag-order Wt[it][nsg][lane][8] bf16; block 567 builds conv0 B-table + zero page.
template<int CIN, int COUT>
__device__ __forceinline__ void wprep_body(
    const float* __restrict__ k, unsigned short* __restrict__ wt, int blk)
{
    constexpr int NS = COUT / 16;
    constexpr int KS = CIN / 32;
    int idx = blk * 256 + (int)threadIdx.x;
    if (idx >= 27 * KS * NS * 64) return;
    int lane = idx & 63;
    int nsg  = (idx >> 6) % NS;
    int it   = idx / (64 * NS);
    int tap  = it / KS;
    int ks   = it - tap * KS;
    int sg = lane >> 4, lr = lane & 15;
    int cout = nsg * 16 + lr;
    ushort8v o;
    #pragma unroll
    for (int j = 0; j < 8; ++j) {
        int ci = ks * 32 + sg * 8 + j;
        o[j] = f2bf(k[(size_t)(tap * CIN + ci) * COUT + cout]);
    }
    *reinterpret_cast<ushort8v*>(wt + (size_t)idx * 8) = o;
}

__global__ __launch_bounds__(256) void wprep_all(
    const float* __restrict__ k0,
    const float* __restrict__ k1, const float* __restrict__ k2, const float* __restrict__ k3,
    unsigned short* __restrict__ w0f,
    unsigned short* __restrict__ w1, unsigned short* __restrict__ w2, unsigned short* __restrict__ w3,
    unsigned short* __restrict__ zp)
{
    int b = blockIdx.x;
    if (b < 27)       wprep_body<32, 64>(k1, w1, b);
    else if (b < 135) wprep_body<64, 128>(k2, w2, b - 27);
    else if (b < 567) wprep_body<128, 256>(k3, w3, b - 135);
    else {
        reinterpret_cast<unsigned int*>(zp)[threadIdx.x] = 0u;   // 1KB zero page
        if (threadIdx.x < 128) {
            int ns = threadIdx.x >> 6, lane = threadIdx.x & 63;
            int sg = lane >> 4, lr = lane & 15;
            ushort8v o;
            #pragma unroll
            for (int j = 0; j < 8; ++j) {
                int t = sg * 8 + j;
                o[j] = (t < 27) ? f2bf(k0[t * 32 + ns * 16 + lr]) : (unsigned short)0;
            }
            *reinterpret_cast<ushort8v*>(w0f + (ns * 64 + lane) * 8) = o;
        }
    }
}

// ---------------- Block 0: LDS-tiled im2col MFMA.
// Block = 4od x 4oh x 16ow output voxels; input tile 9x9x33 fp32 staged once
// via global_load_lds (coalesced, each element read once); lanes gather taps
// from LDS. Pad rows/cols come from the zero page / zslot.
__global__ __launch_bounds__(256) void conv0_lds(
    const float* __restrict__ x, const unsigned short* __restrict__ w0f,
    const float* __restrict__ zf,
    const float* __restrict__ b, const float* __restrict__ g,
    const float* __restrict__ be, const float* __restrict__ m,
    const float* __restrict__ v, unsigned short* __restrict__ y)
{
    __shared__ __attribute__((aligned(16))) float tile[81 * 32];  // 10368 B
    __shared__ float side[84];                                    // 33rd col, 81 used
    __shared__ float zslot;

    const int l   = threadIdx.x & 63;
    const int wid = threadIdx.x >> 6;
    const int sg  = l >> 4;
    const int lr  = l & 15;

    int bb = blockIdx.x;
    const int owt = bb % 3;  bb /= 3;
    const int oht = bb % 12; bb /= 12;
    const int odt = bb % 12; const int n = bb / 12;

    const int id0 = odt * 8, ih0 = oht * 8, iw0 = owt * 32;

    if (threadIdx.x == 0) zslot = 0.f;

    // ---- stage main: 648 16B chunks (tile[81][32] floats)
    #pragma unroll
    for (int q0 = 0; q0 < 648; q0 += 256) {
        int qq = q0 + wid * 64;
        int q = qq + l;
        if (qq < 648 && q < 648) {
            int row = q >> 3, c = q & 7;
            int dd = row / 9, hh = row - dd * 9;
            int id = id0 + dd, ih = ih0 + hh;
            const float* src = (id < 96 && ih < 96)
                ? x + ((size_t)(n * 96 + id) * 96 + ih) * 96 + iw0 + c * 4
                : zf;
            GLOAD_LDS16(src, (char*)tile + (size_t)qq * 16);
        }
    }
    // ---- stage side column (element 32 of each row)
    {
        int row = (wid == 0) ? l : ((wid == 1 && l < 17) ? 64 + l : -1);
        if (row >= 0) {
            int dd = row / 9, hh = row - dd * 9;
            int id = id0 + dd, ih = ih0 + hh;
            const float* src = (id < 96 && ih < 96 && iw0 + 32 < 96)
                ? x + ((size_t)(n * 96 + id) * 96 + ih) * 96 + iw0 + 32
                : zf;
            GLOAD_LDS4(src, (char*)side + (wid == 0 ? 0 : 256));
        }
    }
    __syncthreads();

    const short8v B0 = *(const short8v*)(w0f + l * 8);
    const short8v B1 = *(const short8v*)(w0f + (64 + l) * 8);

    // per-lane tap decomposition (lane-constant across mi)
    int ej[8], wwj[8];
    bool validj[8], sidej[8];
    #pragma unroll
    for (int j = 0; j < 8; ++j) {
        int tap = sg * 8 + j;
        int t = (tap < 27) ? tap : 0;
        int kd = t / 9, r9 = t - kd * 9, kh = r9 / 3, kw = r9 - kh * 3;
        ej[j] = kd * 9 + kh;
        wwj[j] = 2 * lr + kw;
        sidej[j] = (wwj[j] >= 32);
        validj[j] = (tap < 27);
    }

    f32x4 acc[4][2];
    #pragma unroll
    for (int mi = 0; mi < 4; ++mi) {
        acc[mi][0] = (f32x4){0.f, 0.f, 0.f, 0.f};
        acc[mi][1] = (f32x4){0.f, 0.f, 0.f, 0.f};
    }

    #pragma unroll
    for (int mi = 0; mi < 4; ++mi) {
        float av[8];
        #pragma unroll
        for (int j = 0; j < 8; ++j) {
            int row = 18 * wid + 2 * mi + ej[j];
            const float* p = sidej[j] ? &side[row] : &tile[row * 32 + wwj[j]];
            p = validj[j] ? p : &zslot;
            av[j] = *p;
        }
        uint4v au;
        au[0] = cvtpk(av[0], av[1]);
        au[1] = cvtpk(av[2], av[3]);
        au[2] = cvtpk(av[4], av[5]);
        au[3] = cvtpk(av[6], av[7]);
        short8v a = __builtin_bit_cast(short8v, au);
        acc[mi][0] = __builtin_amdgcn_mfma_f32_16x16x32_bf16(a, B0, acc[mi][0], 0, 0, 0);
        acc[mi][1] = __builtin_amdgcn_mfma_f32_16x16x32_bf16(a, B1, acc[mi][1], 0, 0, 0);
    }

    float S[2], T[2];
    #pragma unroll
    for (int ns = 0; ns < 2; ++ns) {
        int c = ns * 16 + lr;
        float sc = g[c] * rsqrtf(v[c] + BN_EPS);
        S[ns] = sc;
        T[ns] = (b[c] - m[c]) * sc + be[c];
    }
    const int odG = odt * 4 + wid;
    #pragma unroll
    for (int mi = 0; mi < 4; ++mi) {
        int oh = oht * 4 + mi;
        unsigned short* yrow =
            y + (((size_t)(n * 48 + odG) * 48 + oh) * 48 + owt * 16) * 32;
        #pragma unroll
        for (int i = 0; i < 4; i += 2) {
            unsigned short* yp0 = yrow + (size_t)(sg * 4 + i) * 32;
            unsigned short* yp1 = yp0 + 32;
            st_pair(yp0 + lr, yp1 + lr,
                    fmaxf(acc[mi][0][i]     * S[0] + T[0], 0.f),
                    fmaxf(acc[mi][0][i + 1] * S[0] + T[0], 0.f));
            st_pair(yp0 + 16 + lr, yp1 + 16 + lr,
                    fmaxf(acc[mi][1][i]     * S[1] + T[1], 0.f),
                    fmaxf(acc[mi][1][i + 1] * S[1] + T[1], 0.f));
        }
    }
}

// ---------------- MFMA implicit-GEMM conv: 3-buffer depth-2 pipeline,
// counted vmcnt + raw s_barrier (never vmcnt(0) in main loop).
template<int CIN, int COUT, int INS, int OUTS, int MW, int NSW, int NH,
         int CSPLIT, int KU>
__global__ __launch_bounds__(256, 2) void conv_mfma_lds(
    const unsigned short* __restrict__ x, const unsigned short* __restrict__ wt,
    const unsigned short* __restrict__ zp,
    const float* __restrict__ b, const float* __restrict__ g,
    const float* __restrict__ be, const float* __restrict__ m,
    const float* __restrict__ v, unsigned short* __restrict__ y)
{
    constexpr int NSfull = COUT / 16;
    constexpr int NSB = NSW * NH;
    constexpr int KS = CIN / 32;
    constexpr int NITK = 27 * KS;
    constexpr int NIT = NITK / KU;
    constexpr int MGROUPS = 4 / NH;
    constexpr int MTILE = MGROUPS * MW * 16;
    constexpr int BSTEP = NSB * KU * 1024;
    constexpr int ASTEP = MGROUPS * MW * KU * 1024;
    constexpr int STRIDE = BSTEP + ASTEP;
    constexpr int BL = (NSB * KU) / 4;
    constexpr int AL = MW * KU;
    static_assert(NSB * CSPLIT == NSfull && NITK % KU == 0 && (NSB * KU) % 4 == 0, "tiling");
    static_assert(NIT >= 3, "pipeline depth");

    __shared__ __attribute__((aligned(16))) char lds[3 * STRIDE];

    const int l   = threadIdx.x & 63;
    const int wid = threadIdx.x >> 6;
    const int sg  = l >> 4;
    const int lr  = l & 15;

    const int mblk   = blockIdx.x / CSPLIT;
    const int cchunk = blockIdx.x % CSPLIT;
    const int mgroup = wid / NH;
    const int ngroup = wid % NH;
    const int gCoutBase = (cchunk * NSB + ngroup * NSW) * 16;
    const int vwave = mblk * MTILE + mgroup * MW * 16;

    const unsigned short* ap0[MW];
    unsigned smask[MW];
    #pragma unroll
    for (int mi = 0; mi < MW; ++mi) {
        int vA = vwave + mi * 16 + lr;
        int owA = vA % OUTS; int t1 = vA / OUTS;
        int ohA = t1 % OUTS; int t2 = t1 / OUTS;
        int odA = t2 % OUTS; int nA = t2 / OUTS;
        ap0[mi] = x + ((((size_t)nA * INS + 2 * odA) * INS + 2 * ohA) * INS + 2 * owA) * CIN + sg * 8;
        smask[mi] = ((odA == OUTS - 1) ? 0x07FC0000u : 0u)
                  | ((ohA == OUTS - 1) ? 0x070381C0u : 0u)
                  | ((owA == OUTS - 1) ? 0x04924924u : 0u);
    }

    const unsigned short* zpl = (const unsigned short*)((const char*)zp + l * 16);

    f32x4 acc[MW][NSW];
    #pragma unroll
    for (int mi = 0; mi < MW; ++mi)
        #pragma unroll
        for (int ns = 0; ns < NSW; ++ns) acc[mi][ns] = (f32x4){0.f, 0.f, 0.f, 0.f};

    auto stage = [&](int ito, int p) {
        char* dst = &lds[p * STRIDE];
        #pragma unroll
        for (int c = 0; c < BL; ++c) {
            int idx  = c * 256 + (int)threadIdx.x;
            int lane = idx & 63;
            int sub  = idx >> 6;
            int u    = sub / NSB;
            int grp  = sub % NSB;
            int it   = ito * KU + u;
            const unsigned short* src =
                wt + ((size_t)(it * NSfull + cchunk * NSB + grp) * 64 + lane) * 8;
            GLOAD_LDS16(src, dst + sub * 1024);
        }
        if (ngroup == 0) {
            #pragma unroll
            for (int u = 0; u < KU; ++u) {
                int it = ito * KU + u;
                int tap = (KS == 1) ? it : it / KS;
                int ks  = (KS == 1) ? 0  : it - tap * KS;
                int kd = tap / 9, r9 = tap - kd * 9, kh = r9 / 3, kw = r9 - kh * 3;
                size_t aoff = (size_t)((kd * INS + kh) * INS + kw) * CIN + ks * 32;
                #pragma unroll
                for (int mi = 0; mi < MW; ++mi) {
                    const unsigned short* ga =
                        ((smask[mi] >> tap) & 1u) ? zpl : (ap0[mi] + aoff);
                    GLOAD_LDS16(ga, dst + BSTEP + ((mgroup * MW + mi) * KU + u) * 1024);
                }
            }
        }
    };

    auto computestep = [&](const char* buf) {
        #pragma unroll
        for (int u = 0; u < KU; ++u) {
            short8v Bf[NSW], Af[MW];
            #pragma unroll
            for (int ns = 0; ns < NSW; ++ns)
                Bf[ns] = *(const short8v*)(buf + (u * NSB + ngroup * NSW + ns) * 1024 + l * 16);
            #pragma unroll
            for (int mi = 0; mi < MW; ++mi)
                Af[mi] = *(const short8v*)(buf + BSTEP + ((mgroup * MW + mi) * KU + u) * 1024 + l * 16);
            #pragma unroll
            for (int mi = 0; mi < MW; ++mi)
                #pragma unroll
                for (int ns = 0; ns < NSW; ++ns)
                    acc[mi][ns] = __builtin_amdgcn_mfma_f32_16x16x32_bf16(Af[mi], Bf[ns], acc[mi][ns], 0, 0, 0);
        }
    };

    stage(0, 0);
    stage(1, 1);
    #pragma unroll 1
    for (int ito = 0; ito < NIT - 1; ++ito) {
        if (ngroup == 0) waitv<BL + AL>(); else waitv<BL>();
        __builtin_amdgcn_s_barrier();
        asm volatile("" ::: "memory");
        if (ito + 2 < NIT) stage(ito + 2, (ito + 2) % 3);
        computestep(&lds[(ito % 3) * STRIDE]);
    }
    waitv<0>();
    __builtin_amdgcn_s_barrier();
    asm volatile("" ::: "memory");
    computestep(&lds[((NIT - 1) % 3) * STRIDE]);

    float S[NSW], T[NSW];
    #pragma unroll
    for (int ns = 0; ns < NSW; ++ns) {
        int c = gCoutBase + ns * 16 + lr;
        float sc = g[c] * rsqrtf(v[c] + BN_EPS);
        S[ns] = sc;
        T[ns] = (b[c] - m[c]) * sc + be[c];
    }
    #pragma unroll
    for (int mi = 0; mi < MW; ++mi) {
        #pragma unroll
        for (int i = 0; i < 4; i += 2) {
            int vD0 = vwave + mi * 16 + sg * 4 + i;
            int vD1 = vD0 + 1;
            int ow0 = vD0 % OUTS; int u1 = vD0 / OUTS;
            int oh0 = u1 % OUTS; int u2 = u1 / OUTS;
            int od0 = u2 % OUTS; int n0 = u2 / OUTS;
            unsigned short* yp0 =
                y + ((((size_t)n0 * OUTS + od0) * OUTS + oh0) * OUTS + ow0) * COUT + gCoutBase + lr;
            int ow1 = vD1 % OUTS; int w1 = vD1 / OUTS;
            int oh1 = w1 % OUTS; int w2 = w1 / OUTS;
            int od1 = w2 % OUTS; int n1 = w2 / OUTS;
            unsigned short* yp1 =
                y + ((((size_t)n1 * OUTS + od1) * OUTS + oh1) * OUTS + ow1) * COUT + gCoutBase + lr;
            #pragma unroll
            for (int ns = 0; ns < NSW; ++ns)
                st_pair(yp0 + ns * 16, yp1 + ns * 16,
                        fmaxf(acc[mi][ns][i]     * S[ns] + T[ns], 0.f),
                        fmaxf(acc[mi][ns][i + 1] * S[ns] + T[ns], 0.f));
        }
    }
}

// ---------------- Head: mean pool + 1x1 conv + BN/ReLU + 1x1 conv + top2 softmax
__global__ __launch_bounds__(256) void head_kernel(
    const unsigned short* __restrict__ x4,
    const float* __restrict__ w1k, const float* __restrict__ w1b,
    const float* __restrict__ wg,  const float* __restrict__ wbe,
    const float* __restrict__ wm,  const float* __restrict__ wv,
    const float* __restrict__ w2k, const float* __restrict__ w2b,
    float* __restrict__ out)
{
    __shared__ float part[8][256];
    __shared__ float h[256];
    __shared__ float r[256];
    __shared__ float logits[8];

    const int n = blockIdx.x;
    const int t = threadIdx.x;
    const int c8 = t & 31;
    const int pg = t >> 5;

    const unsigned short* xb = x4 + (size_t)n * 216 * 256 + c8 * 8;
    float s[8] = {0.f, 0.f, 0.f, 0.f, 0.f, 0.f, 0.f, 0.f};
    for (int i = pg; i < 216; i += 8) {
        ushort8v v8 = *reinterpret_cast<const ushort8v*>(xb + (size_t)i * 256);
        #pragma unroll
        for (int j = 0; j < 8; ++j) s[j] += bf2f(v8[j]);
    }
    #pragma unroll
    for (int j = 0; j < 8; ++j) part[pg][c8 * 8 + j] = s[j];
    __syncthreads();

    float a = 0.f;
    #pragma unroll
    for (int gi = 0; gi < 8; ++gi) a += part[gi][t];
    h[t] = a * (1.0f / 216.0f);
    __syncthreads();

    float acc = w1b[t];
    #pragma unroll 4
    for (int ci = 0; ci < 256; ++ci) acc += h[ci] * w1k[ci * 256 + t];
    float sc = wg[t] * rsqrtf(wv[t] + BN_EPS);
    acc = (acc - wm[t]) * sc + wbe[t];
    r[t] = fmaxf(acc, 0.f);
    __syncthreads();

    if (t < 8) {
        float a2 = w2b[t];
        for (int ci = 0; ci < 256; ++ci) a2 += r[ci] * w2k[ci * 8 + t];
        logits[t] = a2;
    }
    __syncthreads();

    if (t == 0) {
        float m1 = -INFINITY, m2 = -INFINITY;
        for (int e = 0; e < 8; ++e) {
            float val = logits[e];
            if (val > m1) { m2 = m1; m1 = val; }
            else if (val > m2) { m2 = val; }
        }
        float thr = m2;
        float ex[8]; float sum = 0.f;
        for (int e = 0; e < 8; ++e) {
            float val = (logits[e] >= thr) ? logits[e] : -INFINITY;
            ex[e] = expf(val - m1);
            sum += ex[e];
        }
        float inv = 1.0f / sum;
        for (int e = 0; e < 8; ++e) out[n * 8 + e] = ex[e] * inv;
    }
}

extern "C" void kernel_launch(void* const* d_in, const int* in_sizes, int n_in,
                              void* d_out, int out_size, void* d_ws, size_t ws_size,
                              hipStream_t stream) {
    const float* x   = (const float*)d_in[0];
    const float* k0  = (const float*)d_in[1];
    const float* b0  = (const float*)d_in[2];
    const float* g0  = (const float*)d_in[3];
    const float* be0 = (const float*)d_in[4];
    const float* m0  = (const float*)d_in[5];
    const float* v0  = (const float*)d_in[6];
    const float* k1  = (const float*)d_in[7];
    const float* b1  = (const float*)d_in[8];
    const float* g1  = (const float*)d_in[9];
    const float* be1 = (const float*)d_in[10];
    const float* m1  = (const float*)d_in[11];
    const float* v1  = (const float*)d_in[12];
    const float* k2  = (const float*)d_in[13];
    const float* b2  = (const float*)d_in[14];
    const float* g2  = (const float*)d_in[15];
    const float* be2 = (const float*)d_in[16];
    const float* m2  = (const float*)d_in[17];
    const float* v2  = (const float*)d_in[18];
    const float* k3  = (const float*)d_in[19];
    const float* b3  = (const float*)d_in[20];
    const float* g3  = (const float*)d_in[21];
    const float* be3 = (const float*)d_in[22];
    const float* m3  = (const float*)d_in[23];
    const float* v3  = (const float*)d_in[24];
    const float* w1k = (const float*)d_in[25];
    const float* w1b = (const float*)d_in[26];
    const float* wg  = (const float*)d_in[27];
    const float* wbe = (const float*)d_in[28];
    const float* wm  = (const float*)d_in[29];
    const float* wv  = (const float*)d_in[30];
    const float* w2k = (const float*)d_in[31];
    const float* w2b = (const float*)d_in[32];

    unsigned short* x1  = (unsigned short*)d_ws;
    unsigned short* x2  = x1 + 56623104;
    unsigned short* x3  = x2 + 14155776;
    unsigned short* x4  = x3 + 3538944;
    unsigned short* Wt1 = x4 + 884736;
    unsigned short* Wt2 = Wt1 + 55296;
    unsigned short* Wt3 = Wt2 + 221184;
    unsigned short* zp  = Wt3 + 884736;    // 1KB zero page
    unsigned short* W0f = zp + 512;        // conv0 im2col B table (2KB)

    wprep_all<<<568, 256, 0, stream>>>(k0, k1, k2, k3, W0f, Wt1, Wt2, Wt3, zp);
    conv0_lds<<<6912, 256, 0, stream>>>(x, W0f, (const float*)zp, b0, g0, be0, m0, v0, x1);
    conv_mfma_lds<32, 64, 48, 24, 2, 4, 1, 1, 1><<<1728, 256, 0, stream>>>(x1, Wt1, zp, b1, g1, be1, m1, v1, x2);
    conv_mfma_lds<64, 128, 24, 12, 1, 4, 2, 1, 1><<<864, 256, 0, stream>>>(x2, Wt2, zp, b2, g2, be2, m2, v2, x3);
    conv_mfma_lds<128, 256, 12, 6, 1, 1, 4, 4, 2><<<864, 256, 0, stream>>>(x3, Wt3, zp, b3, g3, be3, m3, v3, x4);
    head_kernel<<<16, 256, 0, stream>>>(x4, w1k, w1b, wg, wbe, wm, wv, w2k, w2b, (float*)d_out);
}